// Round 1
// baseline (812.040 us; speedup 1.0000x reference)
//
#include <hip/hip_runtime.h>
#include <math.h>

// SOINN+ restructured:
//  k_xx   : XX[i][j] = x_i . x_j  (64x64 sample Gram)
//  k_dist : P[j][n] = ||x_j - v_n||^2 vs ORIGINAL V (fp32 tiled GEMM), Q[n] = ||v_n||^2
//  k_sum  : per (sample, 64-node chunk) exact min-2 summaries
//  k_init : node_slot[n] = -1
//  k_seq  : 1 block, 64 sequential steps; clean-chunk summary scan + dirty-chunk
//           rescan; modified rows tracked algebraically (g, q) via XX — V never rewritten.

#define N_NODES 100000
#define DIM     256
#define NS      64
#define NCH     1563          // ceil(100000/64)
#define NT      256           // nodes per k_dist block
#define KC      32

__device__ __forceinline__ void merge2(float& a0, int& ai0, float& a1, int& ai1,
                                       float b0, int bi0, float b1, int bi1) {
  // merge two ascending top-2 pairs; tie-break on lower index
  bool bf = (b0 < a0) || (b0 == a0 && bi0 < ai0);
  float n0 = bf ? b0 : a0;  int ni0 = bf ? bi0 : ai0;
  float c0 = bf ? a0 : b0;  int ci0 = bf ? ai0 : bi0;   // loser of firsts
  float c1 = bf ? b1 : a1;  int ci1 = bf ? bi1 : ai1;   // winner's second
  bool sf = (c0 < c1) || (c0 == c1 && ci0 < ci1);
  a0 = n0; ai0 = ni0;
  a1 = sf ? c0 : c1; ai1 = sf ? ci0 : ci1;
}

__global__ void k_xx(const float* __restrict__ X, float* __restrict__ XX) {
  int i = blockIdx.x, j = threadIdx.x;
  const float* xi = X + i * DIM;
  const float* xj = X + j * DIM;
  float acc = 0.f;
  for (int k = 0; k < DIM; k += 4) {
    float4 a = *(const float4*)(xi + k);
    float4 b = *(const float4*)(xj + k);
    acc += a.x * b.x + a.y * b.y + a.z * b.z + a.w * b.w;
  }
  XX[i * NS + j] = acc;
}

__global__ __launch_bounds__(128) void k_dist(const float* __restrict__ X,
                                              const float* __restrict__ V,
                                              const float* __restrict__ XX,
                                              float* __restrict__ P,
                                              float* __restrict__ Q) {
  __shared__ float Xl[KC][NS];    // k-major for conflict-free inner reads
  __shared__ float Vl[KC][NT];
  __shared__ float sq[NT];
  const int tid = threadIdx.x;    // 128 threads
  const int n0  = blockIdx.x * NT;
  const int ty  = tid >> 4;       // 0..7  -> 8 samples each
  const int tx  = tid & 15;       // 0..15 -> 16 nodes each
  float acc[8][16];
#pragma unroll
  for (int i = 0; i < 8; i++)
#pragma unroll
    for (int u = 0; u < 16; u++) acc[i][u] = 0.f;
  float qa0 = 0.f, qa1 = 0.f;

  for (int kc = 0; kc < DIM; kc += KC) {
    __syncthreads();
    const int kk = (tid & 7) * 4;
    // stage X (coalesced global read, transposed LDS write)
#pragma unroll
    for (int i = 0; i < 4; i++) {
      int sl = (tid >> 3) + i * 16;
      float4 x = *(const float4*)(X + sl * DIM + kc + kk);
      Xl[kk + 0][sl] = x.x; Xl[kk + 1][sl] = x.y;
      Xl[kk + 2][sl] = x.z; Xl[kk + 3][sl] = x.w;
    }
    // stage V (coalesced: 8 consecutive lanes cover one node's 32 k-values)
#pragma unroll
    for (int i = 0; i < 16; i++) {
      int nl = (tid >> 3) + i * 16;
      int n  = n0 + nl;
      float4 v = make_float4(0.f, 0.f, 0.f, 0.f);
      if (n < N_NODES) v = *(const float4*)(V + (size_t)n * DIM + kc + kk);
      Vl[kk + 0][nl] = v.x; Vl[kk + 1][nl] = v.y;
      Vl[kk + 2][nl] = v.z; Vl[kk + 3][nl] = v.w;
    }
    __syncthreads();
    // ||v||^2 partials (each thread owns 2 nodes)
#pragma unroll 2
    for (int u = 0; u < 2; u++) {
      int nl = tid * 2 + u;
      float qq = 0.f;
#pragma unroll 8
      for (int k = 0; k < KC; k++) { float t = Vl[k][nl]; qq += t * t; }
      if (u == 0) qa0 += qq; else qa1 += qq;
    }
    // 8x16 register-tile FMA
#pragma unroll 4
    for (int k = 0; k < KC; k++) {
      float xs[8], vs[16];
      *(float4*)&xs[0] = *(const float4*)&Xl[k][ty * 8];
      *(float4*)&xs[4] = *(const float4*)&Xl[k][ty * 8 + 4];
#pragma unroll
      for (int q4 = 0; q4 < 4; q4++)
        *(float4*)&vs[q4 * 4] = *(const float4*)&Vl[k][tx * 16 + q4 * 4];
#pragma unroll
      for (int i = 0; i < 8; i++)
#pragma unroll
        for (int u = 0; u < 16; u++) acc[i][u] += xs[i] * vs[u];
    }
  }
  sq[tid * 2 + 0] = qa0;
  sq[tid * 2 + 1] = qa1;
  __syncthreads();
  if (n0 + tid * 2 + 0 < N_NODES) Q[n0 + tid * 2 + 0] = qa0;
  if (n0 + tid * 2 + 1 < N_NODES) Q[n0 + tid * 2 + 1] = qa1;
  float qs[16];
#pragma unroll
  for (int q4 = 0; q4 < 4; q4++)
    *(float4*)&qs[q4 * 4] = *(const float4*)&sq[tx * 16 + q4 * 4];
  const bool full = (n0 + NT) <= N_NODES;
#pragma unroll
  for (int i = 0; i < 8; i++) {
    int s = ty * 8 + i;
    float xn = XX[s * NS + s];
    float* prow = P + (size_t)s * N_NODES + n0 + tx * 16;
    if (full) {
#pragma unroll
      for (int q4 = 0; q4 < 4; q4++) {
        float4 o;
        o.x = xn - 2.f * acc[i][q4 * 4 + 0] + qs[q4 * 4 + 0];
        o.y = xn - 2.f * acc[i][q4 * 4 + 1] + qs[q4 * 4 + 1];
        o.z = xn - 2.f * acc[i][q4 * 4 + 2] + qs[q4 * 4 + 2];
        o.w = xn - 2.f * acc[i][q4 * 4 + 3] + qs[q4 * 4 + 3];
        *(float4*)(prow + q4 * 4) = o;
      }
    } else {
#pragma unroll
      for (int u = 0; u < 16; u++) {
        int n = n0 + tx * 16 + u;
        if (n < N_NODES) prow[u] = xn - 2.f * acc[i][u] + qs[u];
      }
    }
  }
}

__global__ void k_sum(const float* __restrict__ P, int4* __restrict__ SUM) {
  int gt = blockIdx.x * blockDim.x + threadIdx.x;
  int w = gt >> 6;
  int lane = gt & 63;
  if (w >= NS * NCH) return;
  int j = w / NCH;
  int c = w - j * NCH;
  int n = c * 64 + lane;
  float a0 = (n < N_NODES) ? P[(size_t)j * N_NODES + n] : INFINITY;
  int ai0 = n;
  float a1 = INFINITY; int ai1 = -1;
#pragma unroll
  for (int off = 32; off; off >>= 1) {
    float b0 = __shfl_xor(a0, off, 64);
    int  bi0 = __shfl_xor(ai0, off, 64);
    float b1 = __shfl_xor(a1, off, 64);
    int  bi1 = __shfl_xor(ai1, off, 64);
    merge2(a0, ai0, a1, ai1, b0, bi0, b1, bi1);
  }
  if (lane == 0)
    SUM[w] = make_int4(__float_as_int(a0), ai0, __float_as_int(a1), ai1);
}

__global__ void k_init(int* __restrict__ slot) {
  int i = blockIdx.x * blockDim.x + threadIdx.x;
  if (i < N_NODES) slot[i] = -1;
}

__global__ __launch_bounds__(1024) void k_seq(
    const float* __restrict__ P, const float* __restrict__ Q,
    const float* __restrict__ XXg, const int4* __restrict__ SUM,
    int* __restrict__ node_slot, const int* __restrict__ itp,
    float* __restrict__ out) {
  __shared__ float XX[NS * NS];                 // 16 KB
  __shared__ float g[128][NS];                  // 32 KB tracked-row dot products
  __shared__ float qv[128];
  __shared__ unsigned int dbm[(NCH + 31) / 32]; // dirty-chunk bitmap
  __shared__ int dlist[128];
  __shared__ int ndirty, nslots;
  __shared__ float rv0[16], rv1[16];
  __shared__ int   ri0[16], ri1[16];
  __shared__ int   bidx[2];
  __shared__ int   curslot, newslot;

  const int tid = threadIdx.x;
  for (int i = tid; i < NS * NS; i += 1024) XX[i] = XXg[i];
  for (int i = tid; i < (NCH + 31) / 32; i += 1024) dbm[i] = 0u;
  if (tid == 0) { ndirty = 0; nslots = 0; }
  __syncthreads();
  const int it = itp[0];
  const float eps_b = 1.0f / (float)(it + 2);
  const float eps_n = 1.0f / (float)((it + 1) * 100);

  for (int j = 0; j < NS; j++) {
    const float xnj = XX[j * NS + j];
    float a0 = INFINITY, a1 = INFINITY;
    int ai0 = -1, ai1 = -1;
    // Phase A: clean-chunk summaries
    for (int c = tid; c < NCH; c += 1024) {
      if ((dbm[c >> 5] >> (c & 31)) & 1u) continue;
      int4 sm = SUM[j * NCH + c];
      merge2(a0, ai0, a1, ai1, __int_as_float(sm.x), sm.y,
             __int_as_float(sm.z), sm.w);
    }
    // Phase B: dirty-chunk rescan (tracked rows get fresh algebraic distance)
    const int nd = ndirty;
    for (int t = tid; t < nd * 64; t += 1024) {
      int c = dlist[t >> 6];
      int n = (c << 6) + (t & 63);
      if (n >= N_NODES) continue;
      int sl = node_slot[n];
      float d = (sl >= 0) ? (xnj - 2.f * g[sl][j] + qv[sl])
                          : P[(size_t)j * N_NODES + n];
      merge2(a0, ai0, a1, ai1, d, n, INFINITY, -1);
    }
    // block-wide min-2 reduction
#pragma unroll
    for (int off = 32; off; off >>= 1) {
      float b0 = __shfl_xor(a0, off, 64);
      int  bi0 = __shfl_xor(ai0, off, 64);
      float b1 = __shfl_xor(a1, off, 64);
      int  bi1 = __shfl_xor(ai1, off, 64);
      merge2(a0, ai0, a1, ai1, b0, bi0, b1, bi1);
    }
    if ((tid & 63) == 0) {
      int wv = tid >> 6;
      rv0[wv] = a0; ri0[wv] = ai0; rv1[wv] = a1; ri1[wv] = ai1;
    }
    __syncthreads();
    if (tid == 0) {
      float m0 = rv0[0], m1 = rv1[0]; int mi0 = ri0[0], mi1 = ri1[0];
      for (int wv = 1; wv < 16; wv++)
        merge2(m0, mi0, m1, mi1, rv0[wv], ri0[wv], rv1[wv], ri1[wv]);
      out[j * 2 + 0] = sqrtf(m0 + 1e-12f);
      out[j * 2 + 1] = sqrtf(m1 + 1e-12f);
      bidx[0] = mi0; bidx[1] = mi1;
    }
    __syncthreads();
    // update BMU (eps_b) then sBMU (eps_n) — algebraic, V untouched
    for (int ph = 0; ph < 2; ph++) {
      const int r = bidx[ph];
      const float e = (ph == 0) ? eps_b : eps_n;
      if (tid == 0) {
        int sl = node_slot[r];
        if (sl < 0) {
          sl = nslots++;
          node_slot[r] = sl;
          newslot = 1;
          int c = r >> 6;
          if (!((dbm[c >> 5] >> (c & 31)) & 1u)) {
            dbm[c >> 5] |= (1u << (c & 31));
            dlist[ndirty++] = c;
          }
        } else {
          newslot = 0;
        }
        curslot = sl;
      }
      __syncthreads();
      const int sl = curslot;
      if (newslot) {
        if (tid < NS)
          g[sl][tid] = 0.5f * (XX[tid * NS + tid] + Q[r]
                               - P[(size_t)tid * N_NODES + r]);
        if (tid == 0) qv[sl] = Q[r];
      }
      __syncthreads();
      if (tid == 0) {
        float gj = g[sl][j];        // before g update
        float om = 1.f - e;
        qv[sl] = om * om * qv[sl] + 2.f * e * om * gj + e * e * XX[j * NS + j];
      }
      __syncthreads();
      if (tid < NS)
        g[sl][tid] = (1.f - e) * g[sl][tid] + e * XX[j * NS + tid];
      __syncthreads();
    }
  }
}

extern "C" void kernel_launch(void* const* d_in, const int* in_sizes, int n_in,
                              void* d_out, int out_size, void* d_ws, size_t ws_size,
                              hipStream_t stream) {
  const float* X  = (const float*)d_in[0];  // [64,256]
  const float* V  = (const float*)d_in[1];  // [100000,256]
  const int*  itp = (const int*)d_in[3];    // scalar it
  float* out = (float*)d_out;               // [64,2]

  char* ws = (char*)d_ws;
  size_t off = 0;
  auto alloc = [&](size_t bytes) -> void* {
    size_t o = (off + 255) & ~(size_t)255;
    off = o + bytes;
    return (void*)(ws + o);
  };
  float* P   = (float*)alloc((size_t)NS * N_NODES * sizeof(float)); // 25.6 MB
  float* Q   = (float*)alloc((size_t)N_NODES * sizeof(float));
  float* XXp = (float*)alloc((size_t)NS * NS * sizeof(float));
  int4*  SUM = (int4*)alloc((size_t)NS * NCH * sizeof(int4));
  int*  slot = (int*)alloc((size_t)N_NODES * sizeof(int));

  k_xx  <<<NS, NS, 0, stream>>>(X, XXp);
  k_dist<<<(N_NODES + NT - 1) / NT, 128, 0, stream>>>(X, V, XXp, P, Q);
  k_sum <<<(NS * NCH * 64 + 255) / 256, 256, 0, stream>>>(P, SUM);
  k_init<<<(N_NODES + 255) / 256, 256, 0, stream>>>(slot);
  k_seq <<<1, 1024, 0, stream>>>(P, Q, XXp, SUM, slot, itp, out);
}

// Round 2
// 604.892 us; speedup vs baseline: 1.3425x; 1.3425x over previous
//
#include <hip/hip_runtime.h>
#include <math.h>

// SOINN+ restructured, round 2:
//  k_xx   : XX[i][j] = x_i . x_j  (64x64 sample Gram)
//  k_dist : P[j][n] = ||x_j - v_n||^2 vs ORIGINAL V (fp32 tiled GEMM), Q[n] = ||v_n||^2
//  k_sum  : per (sample, 64-node chunk) exact top-4 (SUM2 = entries 1-2, SUM34 = 3-4)
//  k_seq  : 1 block, 64 sequential steps. Per step: scan chunk summaries filtered by an
//           LDS tracked-node bitmap (top-4 is exact while <=2 tracked nodes per chunk;
//           >=3 -> inline chunk rescan), merge algebraic distances of tracked nodes,
//           2 barriers/step, all updates wave-0-local. SUM rows register-prefetched.

#define N_NODES 100000
#define DIM     256
#define NS      64
#define NCH     1563          // ceil(100000/64)
#define NT      256           // nodes per k_dist block
#define KC      32
#define NBMW    3125          // bitmap words = ceil(100000/32)

__device__ __forceinline__ void merge2(float& a0, int& ai0, float& a1, int& ai1,
                                       float b0, int bi0, float b1, int bi1) {
  // merge two ascending top-2 pairs; tie-break on lower index
  bool bf = (b0 < a0) || (b0 == a0 && bi0 < ai0);
  float n0 = bf ? b0 : a0;  int ni0 = bf ? bi0 : ai0;
  float c0 = bf ? a0 : b0;  int ci0 = bf ? ai0 : bi0;   // loser of firsts
  float c1 = bf ? b1 : a1;  int ci1 = bf ? bi1 : ai1;   // winner's second
  bool sf = (c0 < c1) || (c0 == c1 && ci0 < ci1);
  a0 = n0; ai0 = ni0;
  a1 = sf ? c0 : c1; ai1 = sf ? ci0 : ci1;
}

__global__ void k_xx(const float* __restrict__ X, float* __restrict__ XX) {
  int i = blockIdx.x, j = threadIdx.x;
  const float* xi = X + i * DIM;
  const float* xj = X + j * DIM;
  float acc = 0.f;
  for (int k = 0; k < DIM; k += 4) {
    float4 a = *(const float4*)(xi + k);
    float4 b = *(const float4*)(xj + k);
    acc += a.x * b.x + a.y * b.y + a.z * b.z + a.w * b.w;
  }
  XX[i * NS + j] = acc;
}

__global__ __launch_bounds__(128) void k_dist(const float* __restrict__ X,
                                              const float* __restrict__ V,
                                              const float* __restrict__ XX,
                                              float* __restrict__ P,
                                              float* __restrict__ Q) {
  __shared__ float Xl[KC][NS];    // k-major for conflict-free inner reads
  __shared__ float Vl[KC][NT];
  __shared__ float sq[NT];
  const int tid = threadIdx.x;    // 128 threads
  const int n0  = blockIdx.x * NT;
  const int ty  = tid >> 4;       // 0..7  -> 8 samples each
  const int tx  = tid & 15;       // 0..15 -> 16 nodes each
  float acc[8][16];
#pragma unroll
  for (int i = 0; i < 8; i++)
#pragma unroll
    for (int u = 0; u < 16; u++) acc[i][u] = 0.f;
  float qa0 = 0.f, qa1 = 0.f;

  for (int kc = 0; kc < DIM; kc += KC) {
    __syncthreads();
    const int kk = (tid & 7) * 4;
#pragma unroll
    for (int i = 0; i < 4; i++) {
      int sl = (tid >> 3) + i * 16;
      float4 x = *(const float4*)(X + sl * DIM + kc + kk);
      Xl[kk + 0][sl] = x.x; Xl[kk + 1][sl] = x.y;
      Xl[kk + 2][sl] = x.z; Xl[kk + 3][sl] = x.w;
    }
#pragma unroll
    for (int i = 0; i < 16; i++) {
      int nl = (tid >> 3) + i * 16;
      int n  = n0 + nl;
      float4 v = make_float4(0.f, 0.f, 0.f, 0.f);
      if (n < N_NODES) v = *(const float4*)(V + (size_t)n * DIM + kc + kk);
      Vl[kk + 0][nl] = v.x; Vl[kk + 1][nl] = v.y;
      Vl[kk + 2][nl] = v.z; Vl[kk + 3][nl] = v.w;
    }
    __syncthreads();
#pragma unroll 2
    for (int u = 0; u < 2; u++) {
      int nl = tid * 2 + u;
      float qq = 0.f;
#pragma unroll 8
      for (int k = 0; k < KC; k++) { float t = Vl[k][nl]; qq += t * t; }
      if (u == 0) qa0 += qq; else qa1 += qq;
    }
#pragma unroll 4
    for (int k = 0; k < KC; k++) {
      float xs[8], vs[16];
      *(float4*)&xs[0] = *(const float4*)&Xl[k][ty * 8];
      *(float4*)&xs[4] = *(const float4*)&Xl[k][ty * 8 + 4];
#pragma unroll
      for (int q4 = 0; q4 < 4; q4++)
        *(float4*)&vs[q4 * 4] = *(const float4*)&Vl[k][tx * 16 + q4 * 4];
#pragma unroll
      for (int i = 0; i < 8; i++)
#pragma unroll
        for (int u = 0; u < 16; u++) acc[i][u] += xs[i] * vs[u];
    }
  }
  sq[tid * 2 + 0] = qa0;
  sq[tid * 2 + 1] = qa1;
  __syncthreads();
  if (n0 + tid * 2 + 0 < N_NODES) Q[n0 + tid * 2 + 0] = qa0;
  if (n0 + tid * 2 + 1 < N_NODES) Q[n0 + tid * 2 + 1] = qa1;
  float qs[16];
#pragma unroll
  for (int q4 = 0; q4 < 4; q4++)
    *(float4*)&qs[q4 * 4] = *(const float4*)&sq[tx * 16 + q4 * 4];
  const bool full = (n0 + NT) <= N_NODES;
#pragma unroll
  for (int i = 0; i < 8; i++) {
    int s = ty * 8 + i;
    float xn = XX[s * NS + s];
    float* prow = P + (size_t)s * N_NODES + n0 + tx * 16;
    if (full) {
#pragma unroll
      for (int q4 = 0; q4 < 4; q4++) {
        float4 o;
        o.x = xn - 2.f * acc[i][q4 * 4 + 0] + qs[q4 * 4 + 0];
        o.y = xn - 2.f * acc[i][q4 * 4 + 1] + qs[q4 * 4 + 1];
        o.z = xn - 2.f * acc[i][q4 * 4 + 2] + qs[q4 * 4 + 2];
        o.w = xn - 2.f * acc[i][q4 * 4 + 3] + qs[q4 * 4 + 3];
        *(float4*)(prow + q4 * 4) = o;
      }
    } else {
#pragma unroll
      for (int u = 0; u < 16; u++) {
        int n = n0 + tx * 16 + u;
        if (n < N_NODES) prow[u] = xn - 2.f * acc[i][u] + qs[u];
      }
    }
  }
}

__global__ void k_sum(const float* __restrict__ P, int4* __restrict__ SUM2,
                      int4* __restrict__ SUM34) {
  int gt = blockIdx.x * blockDim.x + threadIdx.x;
  int w = gt >> 6;
  int lane = gt & 63;
  if (w >= NS * NCH) return;
  int j = w / NCH;
  int c = w - j * NCH;
  int n = c * 64 + lane;
  bool valid = (n < N_NODES);
  float dv = valid ? P[(size_t)j * N_NODES + n] : INFINITY;
  int   iv = valid ? n : -1;
  // pass 1: min-2 (butterfly -> all lanes converge)
  float a0 = dv, a1 = INFINITY;
  int ai0 = iv, ai1 = -1;
#pragma unroll
  for (int off = 32; off; off >>= 1) {
    float b0 = __shfl_xor(a0, off, 64);
    int  bi0 = __shfl_xor(ai0, off, 64);
    float b1 = __shfl_xor(a1, off, 64);
    int  bi1 = __shfl_xor(ai1, off, 64);
    merge2(a0, ai0, a1, ai1, b0, bi0, b1, bi1);
  }
  if (lane == 0)
    SUM2[w] = make_int4(__float_as_int(a0), ai0, __float_as_int(a1), ai1);
  // pass 2: exclude entries 1-2 -> entries 3-4
  bool excl = (iv >= 0) && (iv == ai0 || iv == ai1);
  float e0 = excl ? INFINITY : dv;
  int   ei0 = excl ? -1 : iv;
  float e1 = INFINITY; int ei1 = -1;
#pragma unroll
  for (int off = 32; off; off >>= 1) {
    float b0 = __shfl_xor(e0, off, 64);
    int  bi0 = __shfl_xor(ei0, off, 64);
    float b1 = __shfl_xor(e1, off, 64);
    int  bi1 = __shfl_xor(ei1, off, 64);
    merge2(e0, ei0, e1, ei1, b0, bi0, b1, bi1);
  }
  if (lane == 0)
    SUM34[w] = make_int4(__float_as_int(e0), ei0, __float_as_int(e1), ei1);
}

__global__ __launch_bounds__(1024) void k_seq(
    const float* __restrict__ P, const float* __restrict__ Q,
    const float* __restrict__ XXg, const int4* __restrict__ SUM2,
    const int4* __restrict__ SUM34, const int* __restrict__ itp,
    float* __restrict__ out) {
  __shared__ float g[128][NS];                  // 32 KB tracked-row dot products
  __shared__ float qv[128];
  __shared__ unsigned int bitmap[NBMW];         // 12.5 KB tracked-node bitmap
  __shared__ unsigned char tcs[NCH + 1];        // tracked count per chunk
  __shared__ int tracked[128];
  __shared__ float xdiag[NS];
  __shared__ float rv0[16], rv1[16];
  __shared__ int   ri0[16], ri1[16];
  __shared__ int   nslots_sh;

  const int tid = threadIdx.x;
  const int lane = tid & 63;
  const int wv = tid >> 6;
  for (int i = tid; i < NBMW; i += 1024) bitmap[i] = 0u;
  for (int i = tid; i < NCH + 1; i += 1024) tcs[i] = 0;
  if (tid < NS) xdiag[tid] = XXg[tid * NS + tid];
  if (tid == 0) nslots_sh = 0;
  __syncthreads();
  const int it = itp[0];
  const float eps_b = 1.0f / (float)(it + 2);
  const float eps_n = 1.0f / (float)((it + 1) * 100);

  const int c0 = tid;                 // always < NCH (1024 < 1563)
  const int c1 = tid + 1024;         // valid if < NCH
  const bool h1 = (c1 < NCH);
  const int4 inf4 = make_int4(__float_as_int(INFINITY), -1,
                              __float_as_int(INFINITY), -1);
  // prefetch j=0 summary rows
  int4 pf0 = SUM2[c0];
  int4 pf1 = h1 ? SUM2[c1] : inf4;
  int4 pg0 = SUM34[c0];
  int4 pg1 = h1 ? SUM34[c1] : inf4;

  for (int j = 0; j < NS; j++) {
    const float xnj = xdiag[j];
    float a0 = INFINITY, a1 = INFINITY;
    int ai0 = -1, ai1 = -1;
    int4 u0 = pf0, u1 = pf1, v0 = pg0, v1 = pg1;
    // issue next step's prefetch immediately (SUM is immutable)
    if (j + 1 < NS) {
      const int4* b2 = SUM2 + (j + 1) * NCH;
      const int4* b4 = SUM34 + (j + 1) * NCH;
      pf0 = b2[c0]; pg0 = b4[c0];
      if (h1) { pf1 = b2[c1]; pg1 = b4[c1]; }
    }
    // Phase A: chunk summaries filtered by tracked bitmap
#pragma unroll
    for (int cc = 0; cc < 2; cc++) {
      const int c = cc ? c1 : c0;
      if (cc && !h1) break;
      const int4 s2 = cc ? u1 : u0;
      const int4 s4 = cc ? v1 : v0;
      const int t = tcs[c];
      if (t == 0) {
        merge2(a0, ai0, a1, ai1, __int_as_float(s2.x), s2.y,
               __int_as_float(s2.z), s2.w);
      } else if (t <= 2) {
        float dd[4] = {__int_as_float(s2.x), __int_as_float(s2.z),
                       __int_as_float(s4.x), __int_as_float(s4.z)};
        int   ii[4] = {s2.y, s2.w, s4.y, s4.w};
#pragma unroll
        for (int k = 0; k < 4; k++) {
          int id = ii[k];
          bool tr = (id >= 0) && ((bitmap[id >> 5] >> (id & 31)) & 1u);
          if (id >= 0 && !tr) merge2(a0, ai0, a1, ai1, dd[k], id, INFINITY, -1);
        }
      } else {
        // rare: >=3 tracked in chunk -> rescan untracked from P
        int base = c * 64;
        int lim = min(64, N_NODES - base);
        for (int i = 0; i < lim; i++) {
          int n = base + i;
          if ((bitmap[n >> 5] >> (n & 31)) & 1u) continue;
          merge2(a0, ai0, a1, ai1, P[(size_t)j * N_NODES + n], n, INFINITY, -1);
        }
      }
    }
    // tracked nodes: fresh algebraic distances
    const int ns = nslots_sh;
    if (tid < ns) {
      float d = xnj - 2.f * g[tid][j] + qv[tid];
      merge2(a0, ai0, a1, ai1, d, tracked[tid], INFINITY, -1);
    }
    // per-wave butterfly min-2
#pragma unroll
    for (int off = 32; off; off >>= 1) {
      float b0 = __shfl_xor(a0, off, 64);
      int  bi0 = __shfl_xor(ai0, off, 64);
      float b1 = __shfl_xor(a1, off, 64);
      int  bi1 = __shfl_xor(ai1, off, 64);
      merge2(a0, ai0, a1, ai1, b0, bi0, b1, bi1);
    }
    if (lane == 0) { rv0[wv] = a0; ri0[wv] = ai0; rv1[wv] = a1; ri1[wv] = ai1; }
    __syncthreads();
    // wave 0: parallel 16-way merge + all bookkeeping (wave-ordered LDS, no barriers)
    if (wv == 0) {
      float m0 = (lane < 16) ? rv0[lane] : INFINITY;
      float m1 = (lane < 16) ? rv1[lane] : INFINITY;
      int  mi0 = (lane < 16) ? ri0[lane] : -1;
      int  mi1 = (lane < 16) ? ri1[lane] : -1;
#pragma unroll
      for (int off = 8; off; off >>= 1) {
        float b0 = __shfl_xor(m0, off, 64);
        int  bi0 = __shfl_xor(mi0, off, 64);
        float b1 = __shfl_xor(m1, off, 64);
        int  bi1 = __shfl_xor(mi1, off, 64);
        merge2(m0, mi0, m1, mi1, b0, bi0, b1, bi1);
      }
      // lanes 0..15 all converged; broadcast from lane 0
      int   r0 = __shfl(mi0, 0, 64);
      int   r1 = __shfl(mi1, 0, 64);
      if (lane == 0) {
        out[j * 2 + 0] = sqrtf(fmaxf(m0, 0.f) + 1e-12f);
        out[j * 2 + 1] = sqrtf(fmaxf(m1, 0.f) + 1e-12f);
      }
#pragma unroll
      for (int ph = 0; ph < 2; ph++) {
        const int r = ph ? r1 : r0;
        const float e = ph ? eps_n : eps_b;
        const unsigned int w = bitmap[r >> 5];
        const bool isnew = !((w >> (r & 31)) & 1u);
        int sl;
        if (isnew) {
          sl = nslots_sh;
          if (lane == 0) {
            nslots_sh = sl + 1;
            bitmap[r >> 5] = w | (1u << (r & 31));
            tcs[r >> 6] = (unsigned char)(tcs[r >> 6] + 1);
            tracked[sl] = r;
          }
          float qr = Q[r];
          float pv = P[(size_t)lane * N_NODES + r];
          g[sl][lane] = 0.5f * (xdiag[lane] + qr - pv);
          if (lane == 0) qv[sl] = qr;
        } else {
          bool hit0 = (lane < nslots_sh) && (tracked[lane] == r);
          bool hit1 = (lane + 64 < nslots_sh) && (tracked[lane + 64] == r);
          unsigned long long mk0 = __ballot(hit0);
          unsigned long long mk1 = __ballot(hit1);
          sl = mk0 ? (__ffsll(mk0) - 1) : (64 + __ffsll(mk1) - 1);
        }
        // q update (reads g before g update), then g update — same-wave order
        float gj = g[sl][j];
        if (lane == 0) {
          float om = 1.f - e;
          qv[sl] = om * om * qv[sl] + 2.f * e * om * gj + e * e * xnj;
        }
        float xr = XXg[j * NS + lane];     // XX[j][lane], coalesced, L2-hot
        g[sl][lane] = (1.f - e) * g[sl][lane] + e * xr;
      }
    }
    __syncthreads();
  }
}

extern "C" void kernel_launch(void* const* d_in, const int* in_sizes, int n_in,
                              void* d_out, int out_size, void* d_ws, size_t ws_size,
                              hipStream_t stream) {
  const float* X  = (const float*)d_in[0];  // [64,256]
  const float* V  = (const float*)d_in[1];  // [100000,256]
  const int*  itp = (const int*)d_in[3];    // scalar it
  float* out = (float*)d_out;               // [64,2]

  char* ws = (char*)d_ws;
  size_t off = 0;
  auto alloc = [&](size_t bytes) -> void* {
    size_t o = (off + 255) & ~(size_t)255;
    off = o + bytes;
    return (void*)(ws + o);
  };
  float* P    = (float*)alloc((size_t)NS * N_NODES * sizeof(float)); // 25.6 MB
  float* Q    = (float*)alloc((size_t)N_NODES * sizeof(float));
  float* XXp  = (float*)alloc((size_t)NS * NS * sizeof(float));
  int4*  SUM2 = (int4*)alloc((size_t)NS * NCH * sizeof(int4));
  int4*  SUM34= (int4*)alloc((size_t)NS * NCH * sizeof(int4));

  k_xx  <<<NS, NS, 0, stream>>>(X, XXp);
  k_dist<<<(N_NODES + NT - 1) / NT, 128, 0, stream>>>(X, V, XXp, P, Q);
  k_sum <<<(NS * NCH * 64 + 255) / 256, 256, 0, stream>>>(P, SUM2, SUM34);
  k_seq <<<1, 1024, 0, stream>>>(P, Q, XXp, SUM2, SUM34, itp, out);
}

// Round 3
// 573.311 us; speedup vs baseline: 1.4164x; 1.0551x over previous
//
#include <hip/hip_runtime.h>
#include <math.h>

// SOINN+ restructured, round 3:
//  k_xx   : XX[i][j] = x_i . x_j  (unchanged -> bitwise-identical XX)
//  k_dist : P[j][n] = ||x_j - v_n||^2 vs ORIGINAL V, PT = P transposed ([n][j]),
//           Q[n] = ||v_n||^2.  NT=128, 128 thr, 8x8 tile, 782 blocks (12 waves/CU).
//           Per-element FMA order (k ascending) and epilogue expressions preserved
//           bitwise vs round 2 -> P values identical -> identical BMU selections.
//  k_sum  : exact sorted top-4 per (sample, 64-node chunk), u64-packed (dist,idx),
//           coalesced float4 loads, Batcher partial merges.
//  k_seq  : 1 block x 256 thr, 64 sequential steps; u64 min-2, bitmap-filtered
//           summary scan, PT-row (contiguous) new-slot init, single load round-trip
//           for both BMU/sBMU updates.

#define N_NODES 100000
#define DIM     256
#define NS      64
#define NCH     1563          // ceil(100000/64)
#define NCHG    391           // ceil(NCH/4): 4 chunks per wave in k_sum
#define KC      32
#define NBMW    3125          // bitmap words = ceil(100000/32)

typedef unsigned long long u64;

__device__ __forceinline__ u64 pk(float d, int i) {
  // positive floats: bit pattern is order-preserving; (dist, idx) lexicographic
  return ((u64)__float_as_uint(d) << 32) | (unsigned)i;
}
__device__ __forceinline__ u64 umin(u64 a, u64 b) { return a < b ? a : b; }
__device__ __forceinline__ u64 umax(u64 a, u64 b) { return a > b ? a : b; }

__global__ void k_xx(const float* __restrict__ X, float* __restrict__ XX) {
  int i = blockIdx.x, j = threadIdx.x;
  const float* xi = X + i * DIM;
  const float* xj = X + j * DIM;
  float acc = 0.f;
  for (int k = 0; k < DIM; k += 4) {
    float4 a = *(const float4*)(xi + k);
    float4 b = *(const float4*)(xj + k);
    acc += a.x * b.x + a.y * b.y + a.z * b.z + a.w * b.w;
  }
  XX[i * NS + j] = acc;
}

__global__ __launch_bounds__(128) void k_dist(const float* __restrict__ X,
                                              const float* __restrict__ V,
                                              const float* __restrict__ XX,
                                              float* __restrict__ P,
                                              float* __restrict__ PT,
                                              float* __restrict__ Q) {
  __shared__ float Xl[KC][68];    // 64 samples + pad4 (16B-aligned rows)
  __shared__ float Vl[KC][132];   // 128 nodes + pad4
  __shared__ float sq[128];
  const int tid = threadIdx.x;    // 128 threads
  const int n0  = blockIdx.x * 128;
  const int ty  = tid >> 4;       // 0..7  -> samples 8ty..8ty+7
  const int tx  = tid & 15;       // 0..15 -> nodes 8tx..8tx+7
  float acc[8][8];
#pragma unroll
  for (int i = 0; i < 8; i++)
#pragma unroll
    for (int u = 0; u < 8; u++) acc[i][u] = 0.f;
  float qa = 0.f;
  const int xsl = tid >> 1;        // 0..63
  const int xkk = (tid & 1) * 16;

  for (int kc = 0; kc < DIM; kc += KC) {
    __syncthreads();
    // stage X (64 x 32 chunk), transposed to k-major
#pragma unroll
    for (int m = 0; m < 4; m++) {
      float4 x = *(const float4*)(X + xsl * DIM + kc + xkk + 4 * m);
      Xl[xkk + 4 * m + 0][xsl] = x.x; Xl[xkk + 4 * m + 1][xsl] = x.y;
      Xl[xkk + 4 * m + 2][xsl] = x.z; Xl[xkk + 4 * m + 3][xsl] = x.w;
    }
    // stage V (128 x 32 chunk): each thread one node row chunk (128 B contiguous)
    {
      int n = n0 + tid;
      bool ok = (n < N_NODES);
      const float* vp = V + (size_t)n * DIM + kc;
#pragma unroll
      for (int m = 0; m < 8; m++) {
        float4 v = ok ? *(const float4*)(vp + 4 * m) : make_float4(0.f, 0.f, 0.f, 0.f);
        Vl[4 * m + 0][tid] = v.x; Vl[4 * m + 1][tid] = v.y;
        Vl[4 * m + 2][tid] = v.z; Vl[4 * m + 3][tid] = v.w;
      }
    }
    __syncthreads();
    // ||v||^2 chunk partial (node = tid) — same per-node op order as round 2
    {
      float qq = 0.f;
#pragma unroll 8
      for (int k = 0; k < KC; k++) { float t = Vl[k][tid]; qq += t * t; }
      qa += qq;
    }
    // 8x8 register-tile FMA, k ascending (per-element order identical to round 2)
#pragma unroll 4
    for (int k = 0; k < KC; k++) {
      float xs[8], vs[8];
      *(float4*)&xs[0] = *(const float4*)&Xl[k][ty * 8];
      *(float4*)&xs[4] = *(const float4*)&Xl[k][ty * 8 + 4];
      *(float4*)&vs[0] = *(const float4*)&Vl[k][tx * 8];
      *(float4*)&vs[4] = *(const float4*)&Vl[k][tx * 8 + 4];
#pragma unroll
      for (int i = 0; i < 8; i++)
#pragma unroll
        for (int u = 0; u < 8; u++) acc[i][u] += xs[i] * vs[u];
    }
  }
  sq[tid] = qa;
  __syncthreads();
  if (n0 + tid < N_NODES) Q[n0 + tid] = qa;
  float qs[8];
  *(float4*)&qs[0] = *(const float4*)&sq[tx * 8];
  *(float4*)&qs[4] = *(const float4*)&sq[tx * 8 + 4];
  const bool full = (n0 + 128) <= N_NODES;
  // overwrite acc with o = xn - 2*acc + q  (expression preserved from round 2)
#pragma unroll
  for (int i = 0; i < 8; i++) {
    int s = ty * 8 + i;
    float xn = XX[s * NS + s];
#pragma unroll
    for (int u = 0; u < 8; u++) acc[i][u] = xn - 2.f * acc[i][u] + qs[u];
    float* prow = P + (size_t)s * N_NODES + n0 + tx * 8;
    if (full) {
      *(float4*)(prow)     = make_float4(acc[i][0], acc[i][1], acc[i][2], acc[i][3]);
      *(float4*)(prow + 4) = make_float4(acc[i][4], acc[i][5], acc[i][6], acc[i][7]);
    } else {
#pragma unroll
      for (int u = 0; u < 8; u++) {
        int n = n0 + tx * 8 + u;
        if (n < N_NODES) prow[u] = acc[i][u];
      }
    }
  }
  // PT: same values, node-major rows (contiguous 64 floats per node)
#pragma unroll
  for (int u = 0; u < 8; u++) {
    int n = n0 + tx * 8 + u;
    if (n < N_NODES) {
      float* pt = PT + (size_t)n * NS + ty * 8;
      *(float4*)(pt)     = make_float4(acc[0][u], acc[1][u], acc[2][u], acc[3][u]);
      *(float4*)(pt + 4) = make_float4(acc[4][u], acc[5][u], acc[6][u], acc[7][u]);
    }
  }
}

__global__ __launch_bounds__(256) void k_sum(const float* __restrict__ P,
                                             u64* __restrict__ SUMT) {
  int gw = (blockIdx.x * 256 + threadIdx.x) >> 6;   // global wave id
  int lane = threadIdx.x & 63;
  if (gw >= NS * NCHG) return;
  int j  = gw / NCHG;
  int gc = gw - j * NCHG;            // group of 4 chunks = 256 nodes
  int n = gc * 256 + lane * 4;
  const float* prow = P + (size_t)j * N_NODES;
  u64 a0, a1, a2, a3;
  if (n + 3 < N_NODES) {
    float4 p = *(const float4*)(prow + n);
    a0 = pk(p.x, n); a1 = pk(p.y, n + 1); a2 = pk(p.z, n + 2); a3 = pk(p.w, n + 3);
  } else {
    a0 = (n + 0 < N_NODES) ? pk(prow[n + 0], n + 0) : ~0ull;
    a1 = (n + 1 < N_NODES) ? pk(prow[n + 1], n + 1) : ~0ull;
    a2 = (n + 2 < N_NODES) ? pk(prow[n + 2], n + 2) : ~0ull;
    a3 = (n + 3 < N_NODES) ? pk(prow[n + 3], n + 3) : ~0ull;
  }
  // sort4 network: (0,1)(2,3)(0,2)(1,3)(1,2)
  { u64 t = umin(a0, a1); a1 = umax(a0, a1); a0 = t; }
  { u64 t = umin(a2, a3); a3 = umax(a2, a3); a2 = t; }
  { u64 t = umin(a0, a2); a2 = umax(a0, a2); a0 = t; }
  { u64 t = umin(a1, a3); a3 = umax(a1, a3); a1 = t; }
  { u64 t = umin(a1, a2); a2 = umax(a1, a2); a1 = t; }
  // 4 Batcher partial-merge rounds within each 16-lane group -> sorted top-4
#pragma unroll
  for (int off = 1; off <= 8; off <<= 1) {
    u64 b0 = __shfl_xor(a0, off, 64);
    u64 b1 = __shfl_xor(a1, off, 64);
    u64 b2 = __shfl_xor(a2, off, 64);
    u64 b3 = __shfl_xor(a3, off, 64);
    u64 e0 = umin(a0, b0), et = umax(a0, b0), eu = umin(a2, b2);
    u64 e1 = umin(et, eu), e2 = umax(et, eu);
    u64 o0 = umin(a1, b1), ot = umax(a1, b1), ou = umin(a3, b3);
    u64 o1 = umin(ot, ou);
    a0 = e0;
    a1 = umin(o0, e1);
    a2 = umax(o0, e1);
    a3 = umin(o1, e2);
  }
  if ((lane & 15) == 0) {
    int c = gc * 4 + (lane >> 4);
    if (c < NCH) {
      u64* d = SUMT + ((size_t)j * NCH + c) * 4;
      ulonglong2 w0; w0.x = a0; w0.y = a1;
      ulonglong2 w1; w1.x = a2; w1.y = a3;
      *(ulonglong2*)(d)     = w0;
      *(ulonglong2*)(d + 2) = w1;
    }
  }
}

__global__ __launch_bounds__(256) void k_seq(
    const float* __restrict__ P, const float* __restrict__ PT,
    const float* __restrict__ Q, const float* __restrict__ XXg,
    const u64* __restrict__ SUMT, const int* __restrict__ itp,
    float* __restrict__ out) {
  __shared__ float XXl[NS * NS];                // 16 KB
  __shared__ float g[128][NS + 1];              // 33 KB (pad: kill 64-stride conflicts)
  __shared__ float qv[128];
  __shared__ unsigned int bitmap[NBMW];         // 12.5 KB tracked-node bitmap
  __shared__ int tcs[NCH + 1];                  // tracked count per chunk
  __shared__ int tracked[128];
  __shared__ u64 wr0[4], wr1[4];
  __shared__ int nslots_sh;

  const int tid = threadIdx.x;                  // 256 threads = 4 waves
  const int lane = tid & 63;
  const int wv = tid >> 6;
  for (int i = tid; i < NS * NS; i += 256) XXl[i] = XXg[i];
  for (int i = tid; i < NBMW; i += 256) bitmap[i] = 0u;
  for (int i = tid; i < NCH + 1; i += 256) tcs[i] = 0;
  if (tid == 0) nslots_sh = 0;
  __syncthreads();
  const int it = itp[0];
  const float eps_b = 1.0f / (float)(it + 2);
  const float eps_n = 1.0f / (float)((it + 1) * 100);

  for (int j = 0; j < NS; j++) {
    const float xnj = XXl[j * NS + j];
    // load this step's summaries (7 chunks/thread), then process
    u64 sm[7][4];
#pragma unroll
    for (int t = 0; t < 7; t++) {
      int c = tid + 256 * t;
      if (c < NCH) {
        const u64* sp = SUMT + ((size_t)j * NCH + c) * 4;
        ulonglong2 x0 = *(const ulonglong2*)(sp);
        ulonglong2 x1 = *(const ulonglong2*)(sp + 2);
        sm[t][0] = x0.x; sm[t][1] = x0.y; sm[t][2] = x1.x; sm[t][3] = x1.y;
      } else {
        sm[t][0] = sm[t][1] = sm[t][2] = sm[t][3] = ~0ull;
      }
    }
    const int ns = nslots_sh;
    u64 A0 = ~0ull, A1 = ~0ull;
#pragma unroll
    for (int t = 0; t < 7; t++) {
      int c = tid + 256 * t;
      if (c >= NCH) continue;
      int tc = tcs[c];
      if (tc == 0) {
        u64 b0 = sm[t][0], b1 = sm[t][1];
        u64 m = umax(A0, b0);
        A0 = umin(A0, b0);
        A1 = umin(umin(A1, b1), m);
      } else if (tc <= 2) {
#pragma unroll
        for (int e = 0; e < 4; e++) {
          u64 k = sm[t][e];
          int id = (int)(unsigned)(k & 0xFFFFFFFFull);   // always a valid node
          if (!((bitmap[id >> 5] >> (id & 31)) & 1u)) {
            u64 m = umax(A0, k);
            A0 = umin(A0, k);
            A1 = umin(A1, m);
          }
        }
      } else {
        // rare: >=3 tracked in chunk -> rescan untracked from P
        int base = c * 64;
        int lim = min(64, N_NODES - base);
        for (int i2 = 0; i2 < lim; i2++) {
          int n = base + i2;
          if ((bitmap[n >> 5] >> (n & 31)) & 1u) continue;
          u64 k = pk(P[(size_t)j * N_NODES + n], n);
          u64 m = umax(A0, k);
          A0 = umin(A0, k);
          A1 = umin(A1, m);
        }
      }
    }
    // tracked nodes: fresh algebraic distances (expression preserved)
    if (tid < ns) {
      float d = xnj - 2.f * g[tid][j] + qv[tid];
      u64 k = pk(d, tracked[tid]);
      u64 m = umax(A0, k);
      A0 = umin(A0, k);
      A1 = umin(A1, m);
    }
    // per-wave butterfly min-2 on packed keys
#pragma unroll
    for (int off = 32; off; off >>= 1) {
      u64 B0 = __shfl_xor(A0, off, 64);
      u64 B1 = __shfl_xor(A1, off, 64);
      u64 m = umax(A0, B0);
      A0 = umin(A0, B0);
      A1 = umin(umin(A1, B1), m);
    }
    if (lane == 0) { wr0[wv] = A0; wr1[wv] = A1; }
    __syncthreads();
    if (wv == 0) {
      u64 C0 = (lane < 4) ? wr0[lane] : ~0ull;
      u64 C1 = (lane < 4) ? wr1[lane] : ~0ull;
#pragma unroll
      for (int off = 1; off <= 2; off <<= 1) {
        u64 B0 = __shfl_xor(C0, off, 64);
        u64 B1 = __shfl_xor(C1, off, 64);
        u64 m = umax(C0, B0);
        C0 = umin(C0, B0);
        C1 = umin(umin(C1, B1), m);
      }
      u64 k0 = __shfl(C0, 0, 64);
      u64 k1 = __shfl(C1, 0, 64);
      int r0 = (int)(unsigned)(k0 & 0xFFFFFFFFull);
      int r1 = (int)(unsigned)(k1 & 0xFFFFFFFFull);
      if (lane == 0) {
        float m0 = __uint_as_float((unsigned)(k0 >> 32));
        float m1 = __uint_as_float((unsigned)(k1 >> 32));
        out[j * 2 + 0] = sqrtf(fmaxf(m0, 0.f) + 1e-12f);
        out[j * 2 + 1] = sqrtf(fmaxf(m1, 0.f) + 1e-12f);
      }
      // ---- bookkeeping: both phases, loads issued together (r0 != r1 always)
      bool new0 = !((bitmap[r0 >> 5] >> (r0 & 31)) & 1u);
      bool new1 = !((bitmap[r1 >> 5] >> (r1 & 31)) & 1u);
      int sl0, sl1;
      {
        bool h0a = (lane < ns) && (tracked[lane] == r0);
        bool h0b = (lane + 64 < ns) && (tracked[lane + 64] == r0);
        u64 mk0a = __ballot(h0a), mk0b = __ballot(h0b);
        sl0 = new0 ? ns : (mk0a ? (__ffsll(mk0a) - 1) : (64 + __ffsll(mk0b) - 1));
        bool h1a = (lane < ns) && (tracked[lane] == r1);
        bool h1b = (lane + 64 < ns) && (tracked[lane + 64] == r1);
        u64 mk1a = __ballot(h1a), mk1b = __ballot(h1b);
        sl1 = new1 ? (ns + (new0 ? 1 : 0))
                   : (mk1a ? (__ffsll(mk1a) - 1) : (64 + __ffsll(mk1b) - 1));
      }
      float q0 = 0.f, p0v = 0.f, q1 = 0.f, p1v = 0.f;
      if (new0) { q0 = Q[r0]; p0v = PT[(size_t)r0 * NS + lane]; }
      if (new1) { q1 = Q[r1]; p1v = PT[(size_t)r1 * NS + lane]; }
      float xrow = XXl[j * NS + lane];
      float xdl  = XXl[lane * NS + lane];
      if (new0) { g[sl0][lane] = 0.5f * (xdl + q0 - p0v); if (lane == 0) qv[sl0] = q0; }
      if (new1) { g[sl1][lane] = 0.5f * (xdl + q1 - p1v); if (lane == 0) qv[sl1] = q1; }
      float gj0 = g[sl0][j];        // read BEFORE g updates (slots distinct)
      float gj1 = g[sl1][j];
      if (lane == 0) {
        float om = 1.f - eps_b;
        qv[sl0] = om * om * qv[sl0] + 2.f * eps_b * om * gj0 + eps_b * eps_b * xnj;
        float on = 1.f - eps_n;
        qv[sl1] = on * on * qv[sl1] + 2.f * eps_n * on * gj1 + eps_n * eps_n * xnj;
        tracked[sl0] = r0;
        tracked[sl1] = r1;
        if (new0) { bitmap[r0 >> 5] |= 1u << (r0 & 31); tcs[r0 >> 6] += 1; }
        if (new1) { bitmap[r1 >> 5] |= 1u << (r1 & 31); tcs[r1 >> 6] += 1; }
        nslots_sh = ns + (new0 ? 1 : 0) + (new1 ? 1 : 0);
      }
      g[sl0][lane] = (1.f - eps_b) * g[sl0][lane] + eps_b * xrow;
      g[sl1][lane] = (1.f - eps_n) * g[sl1][lane] + eps_n * xrow;
    }
    __syncthreads();
  }
}

extern "C" void kernel_launch(void* const* d_in, const int* in_sizes, int n_in,
                              void* d_out, int out_size, void* d_ws, size_t ws_size,
                              hipStream_t stream) {
  const float* X  = (const float*)d_in[0];  // [64,256]
  const float* V  = (const float*)d_in[1];  // [100000,256]
  const int*  itp = (const int*)d_in[3];    // scalar it
  float* out = (float*)d_out;               // [64,2]

  char* ws = (char*)d_ws;
  size_t off = 0;
  auto alloc = [&](size_t bytes) -> void* {
    size_t o = (off + 255) & ~(size_t)255;
    off = o + bytes;
    return (void*)(ws + o);
  };
  float* P    = (float*)alloc((size_t)NS * N_NODES * sizeof(float)); // 25.6 MB
  float* PT   = (float*)alloc((size_t)NS * N_NODES * sizeof(float)); // 25.6 MB
  float* Q    = (float*)alloc((size_t)N_NODES * sizeof(float));
  float* XXp  = (float*)alloc((size_t)NS * NS * sizeof(float));
  u64*   SUMT = (u64*)alloc((size_t)NS * NCH * 4 * sizeof(u64));     // 3.2 MB

  k_xx  <<<NS, NS, 0, stream>>>(X, XXp);
  k_dist<<<(N_NODES + 127) / 128, 128, 0, stream>>>(X, V, XXp, P, PT, Q);
  {
    int waves = NS * NCHG;                       // 25024
    int blocks = (waves * 64 + 255) / 256;       // 6256
    k_sum<<<blocks, 256, 0, stream>>>(P, SUMT);
  }
  k_seq <<<1, 256, 0, stream>>>(P, PT, Q, XXp, SUMT, itp, out);
}

// Round 4
// 442.271 us; speedup vs baseline: 1.8361x; 1.2963x over previous
//
#include <hip/hip_runtime.h>
#include <math.h>

// SOINN+ restructured, round 4:
//  k_xx     : XX[i][j] = x_i . x_j  (unchanged)
//  k_dist   : P, PT, Q as round 3 (bitwise-identical values) + fused per-chunk
//             min (SUMC) in the epilogue.
//  k_thresh : per sample, T[j] = 160th-smallest chunk-min (bitonic 2048); zero cnt.
//             Guarantees >=160 entries of row j have d <= T[j].
//  k_collect: gather all (d,n) with d <= T[j] into cand[j] (ballot-compacted atomics).
//  k_sort   : bitonic-sort candidates, emit sorted top-192 list L[j].
//  k_seq    : ONE wave, 64 steps. Per step: scan 192-entry list (bitmap filter) +
//             <=128 tracked algebraic distances; untracked winners are provably the
//             first untracked list entries -> PT/Q prefetched before selection.
//             Exactness: at step j <=126 nodes are tracked, so untracked min-2 lie in
//             the top-128 of the original row, and the list holds >=160 real entries.

#define N_NODES 100000
#define DIM     256
#define NS      64
#define NCH     1563          // ceil(100000/64)
#define KC      32
#define NBMW    3125          // bitmap words = ceil(100000/32)
#define CAP     4096          // candidate buffer per sample
#define KL      192           // list length per sample

typedef unsigned long long u64;

__device__ __forceinline__ u64 pk(float d, int i) {
  return ((u64)__float_as_uint(d) << 32) | (unsigned)i;
}
__device__ __forceinline__ u64 umin64(u64 a, u64 b) { return a < b ? a : b; }
__device__ __forceinline__ u64 umax64(u64 a, u64 b) { return a > b ? a : b; }

__global__ void k_xx(const float* __restrict__ X, float* __restrict__ XX) {
  int i = blockIdx.x, j = threadIdx.x;
  const float* xi = X + i * DIM;
  const float* xj = X + j * DIM;
  float acc = 0.f;
  for (int k = 0; k < DIM; k += 4) {
    float4 a = *(const float4*)(xi + k);
    float4 b = *(const float4*)(xj + k);
    acc += a.x * b.x + a.y * b.y + a.z * b.z + a.w * b.w;
  }
  XX[i * NS + j] = acc;
}

__global__ __launch_bounds__(128) void k_dist(const float* __restrict__ X,
                                              const float* __restrict__ V,
                                              const float* __restrict__ XX,
                                              float* __restrict__ P,
                                              float* __restrict__ PT,
                                              float* __restrict__ Q,
                                              u64* __restrict__ SUMC) {
  __shared__ float Xl[KC][68];
  __shared__ float Vl[KC][132];
  __shared__ float sq[128];
  const int tid = threadIdx.x;    // 128 threads
  const int n0  = blockIdx.x * 128;
  const int ty  = tid >> 4;       // 0..7  -> samples 8ty..8ty+7
  const int tx  = tid & 15;       // 0..15 -> nodes 8tx..8tx+7
  float acc[8][8];
#pragma unroll
  for (int i = 0; i < 8; i++)
#pragma unroll
    for (int u = 0; u < 8; u++) acc[i][u] = 0.f;
  float qa = 0.f;
  const int xsl = tid >> 1;
  const int xkk = (tid & 1) * 16;

  for (int kc = 0; kc < DIM; kc += KC) {
    __syncthreads();
#pragma unroll
    for (int m = 0; m < 4; m++) {
      float4 x = *(const float4*)(X + xsl * DIM + kc + xkk + 4 * m);
      Xl[xkk + 4 * m + 0][xsl] = x.x; Xl[xkk + 4 * m + 1][xsl] = x.y;
      Xl[xkk + 4 * m + 2][xsl] = x.z; Xl[xkk + 4 * m + 3][xsl] = x.w;
    }
    {
      int n = n0 + tid;
      bool ok = (n < N_NODES);
      const float* vp = V + (size_t)n * DIM + kc;
#pragma unroll
      for (int m = 0; m < 8; m++) {
        float4 v = ok ? *(const float4*)(vp + 4 * m) : make_float4(0.f, 0.f, 0.f, 0.f);
        Vl[4 * m + 0][tid] = v.x; Vl[4 * m + 1][tid] = v.y;
        Vl[4 * m + 2][tid] = v.z; Vl[4 * m + 3][tid] = v.w;
      }
    }
    __syncthreads();
    {
      float qq = 0.f;
#pragma unroll 8
      for (int k = 0; k < KC; k++) { float t = Vl[k][tid]; qq += t * t; }
      qa += qq;
    }
#pragma unroll 4
    for (int k = 0; k < KC; k++) {
      float xs[8], vs[8];
      *(float4*)&xs[0] = *(const float4*)&Xl[k][ty * 8];
      *(float4*)&xs[4] = *(const float4*)&Xl[k][ty * 8 + 4];
      *(float4*)&vs[0] = *(const float4*)&Vl[k][tx * 8];
      *(float4*)&vs[4] = *(const float4*)&Vl[k][tx * 8 + 4];
#pragma unroll
      for (int i = 0; i < 8; i++)
#pragma unroll
        for (int u = 0; u < 8; u++) acc[i][u] += xs[i] * vs[u];
    }
  }
  sq[tid] = qa;
  __syncthreads();
  if (n0 + tid < N_NODES) Q[n0 + tid] = qa;
  float qs[8];
  *(float4*)&qs[0] = *(const float4*)&sq[tx * 8];
  *(float4*)&qs[4] = *(const float4*)&sq[tx * 8 + 4];
  const bool full = (n0 + 128) <= N_NODES;
#pragma unroll
  for (int i = 0; i < 8; i++) {
    int s = ty * 8 + i;
    float xn = XX[s * NS + s];
#pragma unroll
    for (int u = 0; u < 8; u++) acc[i][u] = xn - 2.f * acc[i][u] + qs[u];
    float* prow = P + (size_t)s * N_NODES + n0 + tx * 8;
    if (full) {
      *(float4*)(prow)     = make_float4(acc[i][0], acc[i][1], acc[i][2], acc[i][3]);
      *(float4*)(prow + 4) = make_float4(acc[i][4], acc[i][5], acc[i][6], acc[i][7]);
    } else {
#pragma unroll
      for (int u = 0; u < 8; u++) {
        int n = n0 + tx * 8 + u;
        if (n < N_NODES) prow[u] = acc[i][u];
      }
    }
  }
#pragma unroll
  for (int u = 0; u < 8; u++) {
    int n = n0 + tx * 8 + u;
    if (n < N_NODES) {
      float* pt = PT + (size_t)n * NS + ty * 8;
      *(float4*)(pt)     = make_float4(acc[0][u], acc[1][u], acc[2][u], acc[3][u]);
      *(float4*)(pt + 4) = make_float4(acc[4][u], acc[5][u], acc[6][u], acc[7][u]);
    }
  }
  // fused per-chunk min: chunk = 64 nodes = tx-half of this block's 128
#pragma unroll
  for (int i = 0; i < 8; i++) {
    int s = ty * 8 + i;
    u64 key = ~0ull;
#pragma unroll
    for (int u = 0; u < 8; u++) {
      int n = n0 + tx * 8 + u;
      if (n < N_NODES) key = umin64(key, pk(acc[i][u], n));
    }
#pragma unroll
    for (int off = 1; off <= 4; off <<= 1)
      key = umin64(key, (u64)__shfl_xor((unsigned long long)key, off, 64));
    if ((tx & 7) == 0) {
      int chunk = (n0 >> 6) + (tx >> 3);
      if (chunk < NCH) SUMC[(size_t)s * NCH + chunk] = key;
    }
  }
}

__global__ __launch_bounds__(256) void k_thresh(const u64* __restrict__ SUMC,
                                                float* __restrict__ Td,
                                                int* __restrict__ cnt) {
  __shared__ u64 A[2048];
  const int j = blockIdx.x, tid = threadIdx.x;
  for (int i = tid; i < 2048; i += 256)
    A[i] = (i < NCH) ? SUMC[(size_t)j * NCH + i] : ~0ull;
  __syncthreads();
  for (int k = 2; k <= 2048; k <<= 1)
    for (int s2 = k >> 1; s2 > 0; s2 >>= 1) {
      for (int i = tid; i < 2048; i += 256) {
        int p = i ^ s2;
        if (p > i) {
          u64 a = A[i], b = A[p];
          bool up = ((i & k) == 0);
          if ((a > b) == up) { A[i] = b; A[p] = a; }
        }
      }
      __syncthreads();
    }
  if (tid == 0) {
    Td[j] = __uint_as_float((unsigned)(A[159] >> 32));   // 160th smallest chunk-min
    cnt[j] = 0;
  }
}

__global__ __launch_bounds__(256) void k_collect(const float* __restrict__ P,
                                                 const float* __restrict__ Td,
                                                 int* __restrict__ cnt,
                                                 u64* __restrict__ cand) {
  const int b = blockIdx.x;
  const int j = b & 63;
  const int seg = b >> 6;
  const int tid = threadIdx.x;
  const int lane = tid & 63;
  const int n0 = seg * 1024 + tid * 4;
  const float T = Td[j];
  const float* prow = P + (size_t)j * N_NODES;
  float d[4];
  if (n0 + 3 < N_NODES) {
    float4 p = *(const float4*)(prow + n0);
    d[0] = p.x; d[1] = p.y; d[2] = p.z; d[3] = p.w;
  } else {
#pragma unroll
    for (int e = 0; e < 4; e++) d[e] = (n0 + e < N_NODES) ? prow[n0 + e] : INFINITY;
  }
#pragma unroll
  for (int e = 0; e < 4; e++) {
    bool hit = (n0 + e < N_NODES) && (d[e] <= T);
    u64 mask = __ballot(hit);
    if (!mask) continue;
    int leader = __ffsll((unsigned long long)mask) - 1;
    int cw = __popcll((unsigned long long)mask);
    int base = 0;
    if (lane == leader) base = atomicAdd(&cnt[j], cw);
    base = __shfl(base, leader, 64);
    if (hit) {
      int pos = base + __popcll((unsigned long long)(mask & ((1ull << lane) - 1)));
      if (pos < CAP) cand[(size_t)j * CAP + pos] = pk(d[e], n0 + e);
    }
  }
}

__global__ __launch_bounds__(256) void k_sort(const int* __restrict__ cnt,
                                              const u64* __restrict__ cand,
                                              u64* __restrict__ L) {
  __shared__ u64 A[4096];
  const int j = blockIdx.x, tid = threadIdx.x;
  int n = cnt[j]; if (n > CAP) n = CAP;
  int M = 256; while (M < n) M <<= 1;
  for (int i = tid; i < M; i += 256)
    A[i] = (i < n) ? cand[(size_t)j * CAP + i] : ~0ull;
  __syncthreads();
  for (int k = 2; k <= M; k <<= 1)
    for (int s2 = k >> 1; s2 > 0; s2 >>= 1) {
      for (int i = tid; i < M; i += 256) {
        int p = i ^ s2;
        if (p > i) {
          u64 a = A[i], b = A[p];
          bool up = ((i & k) == 0);
          if ((a > b) == up) { A[i] = b; A[p] = a; }
        }
      }
      __syncthreads();
    }
  for (int i = tid; i < KL; i += 256) L[(size_t)j * KL + i] = A[i];
}

__global__ __launch_bounds__(64) void k_seq(
    const float* __restrict__ PT, const float* __restrict__ Q,
    const float* __restrict__ XXg, const u64* __restrict__ L,
    const int* __restrict__ itp, float* __restrict__ out) {
  __shared__ float XXl[NS * 65];                // padded stride 65
  __shared__ float g[128][65];                  // slot-major, lane-private columns
  __shared__ float qv[128];
  __shared__ unsigned int bitmap[NBMW];
  __shared__ int tracked[128];
  __shared__ int nslots_sh;

  const int lane = threadIdx.x;                 // one wave
  // stage XX (row-padded), clear bitmap
  for (int i4 = lane * 4; i4 < NS * NS; i4 += 64 * 4) {
    int r = i4 >> 6, c = i4 & 63;
    float4 x = *(const float4*)(XXg + i4);
    XXl[r * 65 + c + 0] = x.x; XXl[r * 65 + c + 1] = x.y;
    XXl[r * 65 + c + 2] = x.z; XXl[r * 65 + c + 3] = x.w;
  }
  for (int i = lane; i < NBMW; i += 64) bitmap[i] = 0u;
  if (lane == 0) nslots_sh = 0;
  __syncthreads();
  const float xdl = XXl[lane * 65 + lane];
  const int it = itp[0];
  const float eps_b = 1.0f / (float)(it + 2);
  const float eps_n = 1.0f / (float)((it + 1) * 100);

  // prefetch list row 0
  u64 e0 = L[lane], e1 = L[lane + 64], e2 = L[lane + 128];

  for (int j = 0; j < NS; j++) {
    const float xnj = XXl[j * 65 + j];
    u64 k0c = e0, k1c = e1, k2c = e2;
    if (j + 1 < NS) {          // prefetch next row
      const u64* Lr = L + (size_t)(j + 1) * KL;
      e0 = Lr[lane]; e1 = Lr[lane + 64]; e2 = Lr[lane + 128];
    }
    const int ns = nslots_sh;
    // ---- list-only min-2 (bitmap-filtered)
    u64 A0 = ~0ull, A1 = ~0ull;
    {
      u64 ks[3] = {k0c, k1c, k2c};
#pragma unroll
      for (int t = 0; t < 3; t++) {
        u64 k = ks[t];
        if (k != ~0ull) {
          int id = (int)(unsigned)(k & 0xFFFFFFFFull);
          if (!((bitmap[id >> 5] >> (id & 31)) & 1u)) {
            u64 m = umax64(A0, k);
            A0 = umin64(A0, k);
            A1 = umin64(A1, m);
          }
        }
      }
    }
#pragma unroll
    for (int off = 32; off; off >>= 1) {
      u64 B0 = __shfl_xor((unsigned long long)A0, off, 64);
      u64 B1 = __shfl_xor((unsigned long long)A1, off, 64);
      u64 m = umax64(A0, B0);
      A0 = umin64(A0, B0);
      A1 = umin64(umin64(A1, B1), m);
    }
    const int c0 = (int)(unsigned)(A0 & 0xFFFFFFFFull);
    const int c1 = (int)(unsigned)(A1 & 0xFFFFFFFFull);
    // ---- deterministic prefetch: untracked winners can only be c0, c1
    float pt0 = PT[(size_t)c0 * NS + lane];
    float q0p = Q[c0];
    float pt1 = PT[(size_t)c1 * NS + lane];
    float q1p = Q[c1];
    // ---- tracked algebraic min-2 (expression preserved)
    u64 T0 = ~0ull, T1 = ~0ull;
    if (lane < ns) {
      float d = xnj - 2.f * g[lane][j] + qv[lane];
      T0 = pk(d, tracked[lane]);
    }
    if (lane + 64 < ns) {
      float d = xnj - 2.f * g[lane + 64][j] + qv[lane + 64];
      u64 k = pk(d, tracked[lane + 64]);
      u64 m = umax64(T0, k);
      T0 = umin64(T0, k);
      T1 = umin64(T1, m);
    }
#pragma unroll
    for (int off = 32; off; off >>= 1) {
      u64 B0 = __shfl_xor((unsigned long long)T0, off, 64);
      u64 B1 = __shfl_xor((unsigned long long)T1, off, 64);
      u64 m = umax64(T0, B0);
      T0 = umin64(T0, B0);
      T1 = umin64(umin64(T1, B1), m);
    }
    // merge (A, T) -> global min-2
    u64 k0, k1;
    {
      u64 m = umax64(A0, T0);
      k0 = umin64(A0, T0);
      k1 = umin64(umin64(A1, T1), m);
    }
    const int r0 = (int)(unsigned)(k0 & 0xFFFFFFFFull);
    const int r1 = (int)(unsigned)(k1 & 0xFFFFFFFFull);
    if (lane == 0) {
      float m0 = __uint_as_float((unsigned)(k0 >> 32));
      float m1 = __uint_as_float((unsigned)(k1 >> 32));
      out[j * 2 + 0] = sqrtf(fmaxf(m0, 0.f) + 1e-12f);
      out[j * 2 + 1] = sqrtf(fmaxf(m1, 0.f) + 1e-12f);
    }
    // ---- bookkeeping (all before any bitmap/tracked writes)
    const bool new0 = !((bitmap[r0 >> 5] >> (r0 & 31)) & 1u);
    const bool new1 = !((bitmap[r1 >> 5] >> (r1 & 31)) & 1u);
    int sl0, sl1;
    {
      bool h0a = (lane < ns) && (tracked[lane] == r0);
      bool h0b = (lane + 64 < ns) && (tracked[lane + 64] == r0);
      u64 mk0a = __ballot(h0a), mk0b = __ballot(h0b);
      sl0 = new0 ? ns : (mk0a ? (__ffsll(mk0a) - 1) : (64 + __ffsll(mk0b) - 1));
      bool h1a = (lane < ns) && (tracked[lane] == r1);
      bool h1b = (lane + 64 < ns) && (tracked[lane + 64] == r1);
      u64 mk1a = __ballot(h1a), mk1b = __ballot(h1b);
      sl1 = new1 ? (ns + (new0 ? 1 : 0))
                 : (mk1a ? (__ffsll(mk1a) - 1) : (64 + __ffsll(mk1b) - 1));
    }
    const float xrow = XXl[j * 65 + lane];
    // phase 0: r0 / eps_b   (r0 untracked => r0 == c0)
    {
      float gold = new0 ? (0.5f * (xdl + q0p - pt0)) : g[sl0][lane];
      float qold = new0 ? q0p : qv[sl0];
      float gj = __shfl(gold, j, 64);
      g[sl0][lane] = (1.f - eps_b) * gold + eps_b * xrow;
      if (lane == 0) {
        float om = 1.f - eps_b;
        qv[sl0] = om * om * qold + 2.f * eps_b * om * gj + eps_b * eps_b * xnj;
        tracked[sl0] = r0;
        if (new0) bitmap[r0 >> 5] |= 1u << (r0 & 31);
      }
    }
    // phase 1: r1 / eps_n   (r1 untracked => r1 in {c0, c1})
    {
      float pv = (r1 == c0) ? pt0 : pt1;
      float qq = (r1 == c0) ? q0p : q1p;
      float gold = new1 ? (0.5f * (xdl + qq - pv)) : g[sl1][lane];
      float qold = new1 ? qq : qv[sl1];
      float gj = __shfl(gold, j, 64);
      g[sl1][lane] = (1.f - eps_n) * gold + eps_n * xrow;
      if (lane == 0) {
        float on = 1.f - eps_n;
        qv[sl1] = on * on * qold + 2.f * eps_n * on * gj + eps_n * eps_n * xnj;
        tracked[sl1] = r1;
        if (new1) bitmap[r1 >> 5] |= 1u << (r1 & 31);
        nslots_sh = ns + (new0 ? 1 : 0) + (new1 ? 1 : 0);
      }
    }
    __syncthreads();
  }
}

extern "C" void kernel_launch(void* const* d_in, const int* in_sizes, int n_in,
                              void* d_out, int out_size, void* d_ws, size_t ws_size,
                              hipStream_t stream) {
  const float* X  = (const float*)d_in[0];  // [64,256]
  const float* V  = (const float*)d_in[1];  // [100000,256]
  const int*  itp = (const int*)d_in[3];    // scalar it
  float* out = (float*)d_out;               // [64,2]

  char* ws = (char*)d_ws;
  size_t off = 0;
  auto alloc = [&](size_t bytes) -> void* {
    size_t o = (off + 255) & ~(size_t)255;
    off = o + bytes;
    return (void*)(ws + o);
  };
  float* P    = (float*)alloc((size_t)NS * N_NODES * sizeof(float)); // 25.6 MB
  float* PT   = (float*)alloc((size_t)NS * N_NODES * sizeof(float)); // 25.6 MB
  float* Q    = (float*)alloc((size_t)N_NODES * sizeof(float));
  float* XXp  = (float*)alloc((size_t)NS * NS * sizeof(float));
  u64*   SUMC = (u64*)alloc((size_t)NS * NCH * sizeof(u64));         // 800 KB
  float* Td   = (float*)alloc((size_t)NS * sizeof(float));
  int*   cnt  = (int*)alloc((size_t)NS * sizeof(int));
  u64*   cand = (u64*)alloc((size_t)NS * CAP * sizeof(u64));         // 2 MB
  u64*   Lst  = (u64*)alloc((size_t)NS * KL * sizeof(u64));          // 96 KB

  k_xx     <<<NS, NS, 0, stream>>>(X, XXp);
  k_dist   <<<(N_NODES + 127) / 128, 128, 0, stream>>>(X, V, XXp, P, PT, Q, SUMC);
  k_thresh <<<NS, 256, 0, stream>>>(SUMC, Td, cnt);
  k_collect<<<64 * 98, 256, 0, stream>>>(P, Td, cnt, cand);
  k_sort   <<<NS, 256, 0, stream>>>(cnt, cand, Lst);
  k_seq    <<<1, 64, 0, stream>>>(PT, Q, XXp, Lst, itp, out);
}

// Round 5
// 412.870 us; speedup vs baseline: 1.9668x; 1.0712x over previous
//
#include <hip/hip_runtime.h>
#include <math.h>

// SOINN+ restructured, round 5:
//  k_xx     : XX[i][j] = x_i . x_j  (unchanged)
//  k_dist   : P/PT/Q bitwise-identical to round 4 (same FMA chains), but 256 thr,
//             NT=128, 8x4 tile -> 3126 waves (12/CU) for latency hiding. SUMC fused.
//  k_thresh : 1024 thr bitonic of 2048 chunk-mins -> T[j] = 160th smallest; cnt=0.
//  k_collect: gather d <= T[j] (ballot-compacted atomics).  (unchanged)
//  k_sort   : bitonic -> sorted top-192 list L[j].          (unchanged)
//  k_seq    : ONE wave. Combined (list+tracked) min-2 via DPP reduction
//             (row_shr 1/2/4/8 + bcast15/31, identity-padded -> disjoint windows,
//             exact top-2 in lane 63, readlane broadcast). Speculative PT/Q
//             prefetch one step ahead using the first-8 list indices (known at
//             init); dependent-load fallback only if all 8 leaders are tracked.

#define N_NODES 100000
#define DIM     256
#define NS      64
#define NCH     1563
#define KC      32
#define NBMW    3125
#define CAP     4096
#define KL      192
#define NSPEC   8

typedef unsigned long long u64;

__device__ __forceinline__ u64 pk(float d, int i) {
  return ((u64)__float_as_uint(d) << 32) | (unsigned)i;
}
__device__ __forceinline__ u64 umin64(u64 a, u64 b) { return a < b ? a : b; }
__device__ __forceinline__ u64 umax64(u64 a, u64 b) { return a > b ? a : b; }
__device__ __forceinline__ void mrg2(u64& A0, u64& A1, u64 B0, u64 B1) {
  u64 m = umax64(A0, B0);
  A0 = umin64(A0, B0);
  A1 = umin64(umin64(A1, B1), m);
}

template <int C>
__device__ __forceinline__ u64 dpp64(u64 x) {
  unsigned lo = (unsigned)__builtin_amdgcn_update_dpp(
      (int)0xFFFFFFFF, (int)(unsigned)(x & 0xFFFFFFFFull), C, 0xF, 0xF, false);
  unsigned hi = (unsigned)__builtin_amdgcn_update_dpp(
      (int)0xFFFFFFFF, (int)(unsigned)(x >> 32), C, 0xF, 0xF, false);
  return ((u64)hi << 32) | lo;
}
template <int C>
__device__ __forceinline__ void dpp_round(u64& A0, u64& A1) {
  u64 B0 = dpp64<C>(A0);
  u64 B1 = dpp64<C>(A1);
  mrg2(A0, A1, B0, B1);
}

__global__ void k_xx(const float* __restrict__ X, float* __restrict__ XX) {
  int i = blockIdx.x, j = threadIdx.x;
  const float* xi = X + i * DIM;
  const float* xj = X + j * DIM;
  float acc = 0.f;
  for (int k = 0; k < DIM; k += 4) {
    float4 a = *(const float4*)(xi + k);
    float4 b = *(const float4*)(xj + k);
    acc += a.x * b.x + a.y * b.y + a.z * b.z + a.w * b.w;
  }
  XX[i * NS + j] = acc;
}

__global__ __launch_bounds__(256) void k_dist(const float* __restrict__ X,
                                              const float* __restrict__ V,
                                              const float* __restrict__ XX,
                                              float* __restrict__ P,
                                              float* __restrict__ PT,
                                              float* __restrict__ Q,
                                              u64* __restrict__ SUMC) {
  __shared__ float Xl[KC][68];
  __shared__ float Vl[KC][136];
  __shared__ float sq[128];
  const int tid = threadIdx.x;    // 256 threads
  const int n0  = blockIdx.x * 128;
  const int ty  = tid >> 5;       // 0..7  -> samples 8ty..8ty+7
  const int tx  = tid & 31;       // 0..31 -> nodes 4tx..4tx+3
  float acc[8][4];
#pragma unroll
  for (int i = 0; i < 8; i++)
#pragma unroll
    for (int u = 0; u < 4; u++) acc[i][u] = 0.f;
  float qa = 0.f;
  const int xsl = tid & 63;            // sample row for X staging
  const int xkk = (tid >> 6) * 8;      // 4 waves cover k-offsets 0,8,16,24
  const int vn  = tid & 127;           // node for V staging
  const int vkk = (tid >> 7) * 16;     // 2 half-grids cover k-offsets 0,16

  for (int kc = 0; kc < DIM; kc += KC) {
    __syncthreads();
    // stage X (64 x 32), conflict-free: lane-major columns
#pragma unroll
    for (int m = 0; m < 2; m++) {
      float4 x = *(const float4*)(X + xsl * DIM + kc + xkk + 4 * m);
      Xl[xkk + 4 * m + 0][xsl] = x.x; Xl[xkk + 4 * m + 1][xsl] = x.y;
      Xl[xkk + 4 * m + 2][xsl] = x.z; Xl[xkk + 4 * m + 3][xsl] = x.w;
    }
    // stage V (128 x 32): thread reads one 64B line of its node row
    {
      int n = n0 + vn;
      bool ok = (n < N_NODES);
      const float* vp = V + (size_t)n * DIM + kc + vkk;
#pragma unroll
      for (int m = 0; m < 4; m++) {
        float4 v = ok ? *(const float4*)(vp + 4 * m) : make_float4(0.f, 0.f, 0.f, 0.f);
        Vl[vkk + 4 * m + 0][vn] = v.x; Vl[vkk + 4 * m + 1][vn] = v.y;
        Vl[vkk + 4 * m + 2][vn] = v.z; Vl[vkk + 4 * m + 3][vn] = v.w;
      }
    }
    __syncthreads();
    // ||v||^2 partial — node n0+tid, identical op order to round 4
    if (tid < 128) {
      float qq = 0.f;
#pragma unroll 8
      for (int k = 0; k < KC; k++) { float t = Vl[k][tid]; qq += t * t; }
      qa += qq;
    }
    // 8x4 register-tile FMA, k ascending (per-element chains bitwise preserved)
#pragma unroll 4
    for (int k = 0; k < KC; k++) {
      float xs[8], vs[4];
      *(float4*)&xs[0] = *(const float4*)&Xl[k][ty * 8];
      *(float4*)&xs[4] = *(const float4*)&Xl[k][ty * 8 + 4];
      *(float4*)&vs[0] = *(const float4*)&Vl[k][tx * 4];
#pragma unroll
      for (int i = 0; i < 8; i++)
#pragma unroll
        for (int u = 0; u < 4; u++) acc[i][u] += xs[i] * vs[u];
    }
  }
  if (tid < 128) sq[tid] = qa;
  __syncthreads();
  if (tid < 128 && n0 + tid < N_NODES) Q[n0 + tid] = qa;
  float qs[4];
  *(float4*)&qs[0] = *(const float4*)&sq[tx * 4];
  const bool full = (n0 + 128) <= N_NODES;
#pragma unroll
  for (int i = 0; i < 8; i++) {
    int s = ty * 8 + i;
    float xn = XX[s * NS + s];
#pragma unroll
    for (int u = 0; u < 4; u++) acc[i][u] = xn - 2.f * acc[i][u] + qs[u];
    float* prow = P + (size_t)s * N_NODES + n0 + tx * 4;
    if (full) {
      *(float4*)(prow) = make_float4(acc[i][0], acc[i][1], acc[i][2], acc[i][3]);
    } else {
#pragma unroll
      for (int u = 0; u < 4; u++) {
        int n = n0 + tx * 4 + u;
        if (n < N_NODES) prow[u] = acc[i][u];
      }
    }
  }
#pragma unroll
  for (int u = 0; u < 4; u++) {
    int n = n0 + tx * 4 + u;
    if (n < N_NODES) {
      float* pt = PT + (size_t)n * NS + ty * 8;
      *(float4*)(pt)     = make_float4(acc[0][u], acc[1][u], acc[2][u], acc[3][u]);
      *(float4*)(pt + 4) = make_float4(acc[4][u], acc[5][u], acc[6][u], acc[7][u]);
    }
  }
  // fused per-chunk(64) min: reduce across 16 tx-lanes
#pragma unroll
  for (int i = 0; i < 8; i++) {
    int s = ty * 8 + i;
    u64 key = ~0ull;
#pragma unroll
    for (int u = 0; u < 4; u++) {
      int n = n0 + tx * 4 + u;
      if (n < N_NODES) key = umin64(key, pk(acc[i][u], n));
    }
#pragma unroll
    for (int off = 1; off <= 8; off <<= 1)
      key = umin64(key, (u64)__shfl_xor((unsigned long long)key, off, 64));
    if ((tx & 15) == 0) {
      int chunk = (n0 >> 6) + (tx >> 4);
      if (chunk < NCH) SUMC[(size_t)s * NCH + chunk] = key;
    }
  }
}

__global__ __launch_bounds__(1024) void k_thresh(const u64* __restrict__ SUMC,
                                                 float* __restrict__ Td,
                                                 int* __restrict__ cnt) {
  __shared__ u64 A[2048];
  const int j = blockIdx.x, tid = threadIdx.x;
  for (int i = tid; i < 2048; i += 1024)
    A[i] = (i < NCH) ? SUMC[(size_t)j * NCH + i] : ~0ull;
  __syncthreads();
  for (int k = 2; k <= 2048; k <<= 1)
    for (int s2 = k >> 1; s2 > 0; s2 >>= 1) {
      for (int i = tid; i < 2048; i += 1024) {
        int p = i ^ s2;
        if (p > i) {
          u64 a = A[i], b = A[p];
          bool up = ((i & k) == 0);
          if ((a > b) == up) { A[i] = b; A[p] = a; }
        }
      }
      __syncthreads();
    }
  if (tid == 0) {
    Td[j] = __uint_as_float((unsigned)(A[159] >> 32));
    cnt[j] = 0;
  }
}

__global__ __launch_bounds__(256) void k_collect(const float* __restrict__ P,
                                                 const float* __restrict__ Td,
                                                 int* __restrict__ cnt,
                                                 u64* __restrict__ cand) {
  const int b = blockIdx.x;
  const int j = b & 63;
  const int seg = b >> 6;
  const int tid = threadIdx.x;
  const int lane = tid & 63;
  const int n0 = seg * 1024 + tid * 4;
  const float T = Td[j];
  const float* prow = P + (size_t)j * N_NODES;
  float d[4];
  if (n0 + 3 < N_NODES) {
    float4 p = *(const float4*)(prow + n0);
    d[0] = p.x; d[1] = p.y; d[2] = p.z; d[3] = p.w;
  } else {
#pragma unroll
    for (int e = 0; e < 4; e++) d[e] = (n0 + e < N_NODES) ? prow[n0 + e] : INFINITY;
  }
#pragma unroll
  for (int e = 0; e < 4; e++) {
    bool hit = (n0 + e < N_NODES) && (d[e] <= T);
    u64 mask = __ballot(hit);
    if (!mask) continue;
    int leader = __ffsll((unsigned long long)mask) - 1;
    int cw = __popcll((unsigned long long)mask);
    int base = 0;
    if (lane == leader) base = atomicAdd(&cnt[j], cw);
    base = __shfl(base, leader, 64);
    if (hit) {
      int pos = base + __popcll((unsigned long long)(mask & ((1ull << lane) - 1)));
      if (pos < CAP) cand[(size_t)j * CAP + pos] = pk(d[e], n0 + e);
    }
  }
}

__global__ __launch_bounds__(256) void k_sort(const int* __restrict__ cnt,
                                              const u64* __restrict__ cand,
                                              u64* __restrict__ L) {
  __shared__ u64 A[4096];
  const int j = blockIdx.x, tid = threadIdx.x;
  int n = cnt[j]; if (n > CAP) n = CAP;
  int M = 256; while (M < n) M <<= 1;
  for (int i = tid; i < M; i += 256)
    A[i] = (i < n) ? cand[(size_t)j * CAP + i] : ~0ull;
  __syncthreads();
  for (int k = 2; k <= M; k <<= 1)
    for (int s2 = k >> 1; s2 > 0; s2 >>= 1) {
      for (int i = tid; i < M; i += 256) {
        int p = i ^ s2;
        if (p > i) {
          u64 a = A[i], b = A[p];
          bool up = ((i & k) == 0);
          if ((a > b) == up) { A[i] = b; A[p] = a; }
        }
      }
      __syncthreads();
    }
  for (int i = tid; i < KL; i += 256) L[(size_t)j * KL + i] = A[i];
}

__global__ __launch_bounds__(64) void k_seq(
    const float* __restrict__ PT, const float* __restrict__ Q,
    const float* __restrict__ XXg, const u64* __restrict__ L,
    const int* __restrict__ itp, float* __restrict__ out) {
  __shared__ float XXl[NS * 65];
  __shared__ float g[128][65];
  __shared__ float qv[128];
  __shared__ unsigned int bitmap[NBMW];
  __shared__ int tracked[128];
  __shared__ int fidx[NS][NSPEC];
  __shared__ int nslots_sh;

  const int lane = threadIdx.x;  // one wave
  for (int i4 = lane * 4; i4 < NS * NS; i4 += 64 * 4) {
    int r = i4 >> 6, c = i4 & 63;
    float4 x = *(const float4*)(XXg + i4);
    XXl[r * 65 + c + 0] = x.x; XXl[r * 65 + c + 1] = x.y;
    XXl[r * 65 + c + 2] = x.z; XXl[r * 65 + c + 3] = x.w;
  }
  for (int i = lane; i < NBMW; i += 64) bitmap[i] = 0u;
  // first-8 list indices for every row (speculation targets, known up front)
#pragma unroll
  for (int t = 0; t < NSPEC; t++)
    fidx[lane][t] = (int)(unsigned)(L[(size_t)lane * KL + t] & 0xFFFFFFFFull);
  if (lane == 0) nslots_sh = 0;
  __syncthreads();
  const float xdl = XXl[lane * 65 + lane];
  const int it = itp[0];
  const float eps_b = 1.0f / (float)(it + 2);
  const float eps_n = 1.0f / (float)((it + 1) * 100);

  // prefetch row 0: list entries + speculative PT/Q of first-8 entries
  u64 e0 = L[lane], e1 = L[lane + 64], e2 = L[lane + 128];
  int   sidxC[NSPEC];
  float ptC[NSPEC], qC[NSPEC];
#pragma unroll
  for (int t = 0; t < NSPEC; t++) {
    int id = fidx[0][t];
    sidxC[t] = id;
    ptC[t] = PT[(size_t)id * NS + lane];
    qC[t]  = Q[id];
  }

  for (int j = 0; j < NS; j++) {
    const float xnj = XXl[j * 65 + j];
    u64 k0c = e0, k1c = e1, k2c = e2;
    int   sidxN[NSPEC];
    float ptN[NSPEC], qN[NSPEC];
    if (j + 1 < NS) {   // fire-and-forget next-step prefetches
      const u64* Lr = L + (size_t)(j + 1) * KL;
      e0 = Lr[lane]; e1 = Lr[lane + 64]; e2 = Lr[lane + 128];
#pragma unroll
      for (int t = 0; t < NSPEC; t++) {
        int id = fidx[j + 1][t];
        sidxN[t] = id;
        ptN[t] = PT[(size_t)id * NS + lane];
        qN[t]  = Q[id];
      }
    }
    const int ns = nslots_sh;
    // ---- local candidates: 3 bitmap-filtered list entries + 2 tracked slots
    u64 A0 = ~0ull, A1 = ~0ull;
    {
      u64 ks[3] = {k0c, k1c, k2c};
#pragma unroll
      for (int t = 0; t < 3; t++) {
        u64 k = ks[t];
        if (k != ~0ull) {
          int id = (int)(unsigned)(k & 0xFFFFFFFFull);
          if (!((bitmap[id >> 5] >> (id & 31)) & 1u)) {
            u64 m = umax64(A0, k);
            A0 = umin64(A0, k);
            A1 = umin64(A1, m);
          }
        }
      }
    }
    if (lane < ns) {
      float d = xnj - 2.f * g[lane][j] + qv[lane];
      mrg2(A0, A1, pk(d, tracked[lane]), ~0ull);
    }
    if (lane + 64 < ns) {
      float d = xnj - 2.f * g[lane + 64][j] + qv[lane + 64];
      mrg2(A0, A1, pk(d, tracked[lane + 64]), ~0ull);
    }
    // ---- DPP min-2 reduction (disjoint-window network, exact top-2 in lane 63)
    dpp_round<0x111>(A0, A1);  // row_shr:1
    dpp_round<0x112>(A0, A1);  // row_shr:2
    dpp_round<0x114>(A0, A1);  // row_shr:4
    dpp_round<0x118>(A0, A1);  // row_shr:8
    dpp_round<0x142>(A0, A1);  // row_bcast15
    dpp_round<0x143>(A0, A1);  // row_bcast31
    const unsigned k0lo = (unsigned)__builtin_amdgcn_readlane((int)(unsigned)(A0 & 0xFFFFFFFFull), 63);
    const unsigned k0hi = (unsigned)__builtin_amdgcn_readlane((int)(unsigned)(A0 >> 32), 63);
    const unsigned k1lo = (unsigned)__builtin_amdgcn_readlane((int)(unsigned)(A1 & 0xFFFFFFFFull), 63);
    const unsigned k1hi = (unsigned)__builtin_amdgcn_readlane((int)(unsigned)(A1 >> 32), 63);
    const int r0 = (int)k0lo;
    const int r1 = (int)k1lo;
    if (lane == 0) {
      out[j * 2 + 0] = sqrtf(fmaxf(__uint_as_float(k0hi), 0.f) + 1e-12f);
      out[j * 2 + 1] = sqrtf(fmaxf(__uint_as_float(k1hi), 0.f) + 1e-12f);
    }
    // ---- bookkeeping
    const bool new0 = !((bitmap[r0 >> 5] >> (r0 & 31)) & 1u);
    const bool new1 = !((bitmap[r1 >> 5] >> (r1 & 31)) & 1u);
    int sl0, sl1;
    {
      bool h0a = (lane < ns) && (tracked[lane] == r0);
      bool h0b = (lane + 64 < ns) && (tracked[lane + 64] == r0);
      u64 mk0a = __ballot(h0a), mk0b = __ballot(h0b);
      sl0 = new0 ? ns : (mk0a ? (__ffsll(mk0a) - 1) : (64 + __ffsll(mk0b) - 1));
      bool h1a = (lane < ns) && (tracked[lane] == r1);
      bool h1b = (lane + 64 < ns) && (tracked[lane + 64] == r1);
      u64 mk1a = __ballot(h1a), mk1b = __ballot(h1b);
      sl1 = new1 ? (ns + (new0 ? 1 : 0))
                 : (mk1a ? (__ffsll(mk1a) - 1) : (64 + __ffsll(mk1b) - 1));
    }
    // speculative-hit select (values bitwise identical to a direct load)
    float pv0 = 0.f, qq0 = 0.f, pv1 = 0.f, qq1 = 0.f;
    bool hit0 = false, hit1 = false;
#pragma unroll
    for (int t = 0; t < NSPEC; t++) {
      bool h0 = (sidxC[t] == r0);
      bool h1 = (sidxC[t] == r1);
      pv0 = h0 ? ptC[t] : pv0;  qq0 = h0 ? qC[t] : qq0;  hit0 |= h0;
      pv1 = h1 ? ptC[t] : pv1;  qq1 = h1 ? qC[t] : qq1;  hit1 |= h1;
    }
    if (new0 && !hit0) { pv0 = PT[(size_t)r0 * NS + lane]; qq0 = Q[r0]; }
    if (new1 && !hit1) { pv1 = PT[(size_t)r1 * NS + lane]; qq1 = Q[r1]; }
    const float xrow = XXl[j * 65 + lane];
    // phase 0: r0 / eps_b
    {
      float gold = new0 ? (0.5f * (xdl + qq0 - pv0)) : g[sl0][lane];
      float qold = new0 ? qq0 : qv[sl0];
      float gj = __uint_as_float((unsigned)__builtin_amdgcn_readlane(
          (int)__float_as_uint(gold), j));
      g[sl0][lane] = (1.f - eps_b) * gold + eps_b * xrow;
      if (lane == 0) {
        float om = 1.f - eps_b;
        qv[sl0] = om * om * qold + 2.f * eps_b * om * gj + eps_b * eps_b * xnj;
        tracked[sl0] = r0;
        if (new0) bitmap[r0 >> 5] |= 1u << (r0 & 31);
      }
    }
    // phase 1: r1 / eps_n
    {
      float gold = new1 ? (0.5f * (xdl + qq1 - pv1)) : g[sl1][lane];
      float qold = new1 ? qq1 : qv[sl1];
      float gj = __uint_as_float((unsigned)__builtin_amdgcn_readlane(
          (int)__float_as_uint(gold), j));
      g[sl1][lane] = (1.f - eps_n) * gold + eps_n * xrow;
      if (lane == 0) {
        float on = 1.f - eps_n;
        qv[sl1] = on * on * qold + 2.f * eps_n * on * gj + eps_n * eps_n * xnj;
        tracked[sl1] = r1;
        if (new1) bitmap[r1 >> 5] |= 1u << (r1 & 31);
        nslots_sh = ns + (new0 ? 1 : 0) + (new1 ? 1 : 0);
      }
    }
    // rotate speculation registers
#pragma unroll
    for (int t = 0; t < NSPEC; t++) {
      sidxC[t] = sidxN[t]; ptC[t] = ptN[t]; qC[t] = qN[t];
    }
    __syncthreads();
  }
}

extern "C" void kernel_launch(void* const* d_in, const int* in_sizes, int n_in,
                              void* d_out, int out_size, void* d_ws, size_t ws_size,
                              hipStream_t stream) {
  const float* X  = (const float*)d_in[0];  // [64,256]
  const float* V  = (const float*)d_in[1];  // [100000,256]
  const int*  itp = (const int*)d_in[3];    // scalar it
  float* out = (float*)d_out;               // [64,2]

  char* ws = (char*)d_ws;
  size_t off = 0;
  auto alloc = [&](size_t bytes) -> void* {
    size_t o = (off + 255) & ~(size_t)255;
    off = o + bytes;
    return (void*)(ws + o);
  };
  float* P    = (float*)alloc((size_t)NS * N_NODES * sizeof(float)); // 25.6 MB
  float* PT   = (float*)alloc((size_t)NS * N_NODES * sizeof(float)); // 25.6 MB
  float* Q    = (float*)alloc((size_t)N_NODES * sizeof(float));
  float* XXp  = (float*)alloc((size_t)NS * NS * sizeof(float));
  u64*   SUMC = (u64*)alloc((size_t)NS * NCH * sizeof(u64));         // 800 KB
  float* Td   = (float*)alloc((size_t)NS * sizeof(float));
  int*   cnt  = (int*)alloc((size_t)NS * sizeof(int));
  u64*   cand = (u64*)alloc((size_t)NS * CAP * sizeof(u64));         // 2 MB
  u64*   Lst  = (u64*)alloc((size_t)NS * KL * sizeof(u64));          // 96 KB

  k_xx     <<<NS, NS, 0, stream>>>(X, XXp);
  k_dist   <<<(N_NODES + 127) / 128, 256, 0, stream>>>(X, V, XXp, P, PT, Q, SUMC);
  k_thresh <<<NS, 1024, 0, stream>>>(SUMC, Td, cnt);
  k_collect<<<64 * 98, 256, 0, stream>>>(P, Td, cnt, cand);
  k_sort   <<<NS, 256, 0, stream>>>(cnt, cand, Lst);
  k_seq    <<<1, 64, 0, stream>>>(PT, Q, XXp, Lst, itp, out);
}

// Round 6
// 390.176 us; speedup vs baseline: 2.0812x; 1.0582x over previous
//
#include <hip/hip_runtime.h>
#include <math.h>

// SOINN+ restructured, round 6:
//  k_xx / k_dist / k_thresh / k_collect / k_sort : unchanged from round 5.
//  k_seq: 2 waves, producer/consumer.
//   wave 0 (consumer): pure LDS+VALU step — verdict-filtered list candidates
//     (verdicts precomputed by wave 1, patched with previous step's r0/r1 in regs),
//     tracked algebraic distances, DPP u64 min-2 (exact, verified R5), ballot slot
//     lookup, g/q updates. NO global loads on the critical path.
//   wave 1 (producer), iteration j: stages list j+2 into an LDS ring, scans list
//     j+1 vs bitmap -> verdict masks + first-4-untracked positions, prefetches
//     their PT rows + Q into a double-buffered LDS spec area.
//   Coverage proof: B_{j-1} <= B_scan <= B_j and |B_j - B_{j-1}| <= 2, so the
//     first-2-untracked at step j+1 are within the first-4-untracked at scan time.
//   All distance/update expressions bitwise-identical to round 5 -> absmax 0.

#define N_NODES 100000
#define DIM     256
#define NS      64
#define NCH     1563
#define KC      32
#define NBMW    3125
#define CAP     4096
#define KL      192

typedef unsigned long long u64;

__device__ __forceinline__ u64 pk(float d, int i) {
  return ((u64)__float_as_uint(d) << 32) | (unsigned)i;
}
__device__ __forceinline__ u64 umin64(u64 a, u64 b) { return a < b ? a : b; }
__device__ __forceinline__ u64 umax64(u64 a, u64 b) { return a > b ? a : b; }
__device__ __forceinline__ void mrg2(u64& A0, u64& A1, u64 B0, u64 B1) {
  u64 m = umax64(A0, B0);
  A0 = umin64(A0, B0);
  A1 = umin64(umin64(A1, B1), m);
}

template <int C>
__device__ __forceinline__ u64 dpp64(u64 x) {
  unsigned lo = (unsigned)__builtin_amdgcn_update_dpp(
      (int)0xFFFFFFFF, (int)(unsigned)(x & 0xFFFFFFFFull), C, 0xF, 0xF, false);
  unsigned hi = (unsigned)__builtin_amdgcn_update_dpp(
      (int)0xFFFFFFFF, (int)(unsigned)(x >> 32), C, 0xF, 0xF, false);
  return ((u64)hi << 32) | lo;
}
template <int C>
__device__ __forceinline__ void dpp_round(u64& A0, u64& A1) {
  u64 B0 = dpp64<C>(A0);
  u64 B1 = dpp64<C>(A1);
  mrg2(A0, A1, B0, B1);
}

__global__ void k_xx(const float* __restrict__ X, float* __restrict__ XX) {
  int i = blockIdx.x, j = threadIdx.x;
  const float* xi = X + i * DIM;
  const float* xj = X + j * DIM;
  float acc = 0.f;
  for (int k = 0; k < DIM; k += 4) {
    float4 a = *(const float4*)(xi + k);
    float4 b = *(const float4*)(xj + k);
    acc += a.x * b.x + a.y * b.y + a.z * b.z + a.w * b.w;
  }
  XX[i * NS + j] = acc;
}

__global__ __launch_bounds__(256) void k_dist(const float* __restrict__ X,
                                              const float* __restrict__ V,
                                              const float* __restrict__ XX,
                                              float* __restrict__ P,
                                              float* __restrict__ PT,
                                              float* __restrict__ Q,
                                              u64* __restrict__ SUMC) {
  __shared__ float Xl[KC][68];
  __shared__ float Vl[KC][136];
  __shared__ float sq[128];
  const int tid = threadIdx.x;
  const int n0  = blockIdx.x * 128;
  const int ty  = tid >> 5;
  const int tx  = tid & 31;
  float acc[8][4];
#pragma unroll
  for (int i = 0; i < 8; i++)
#pragma unroll
    for (int u = 0; u < 4; u++) acc[i][u] = 0.f;
  float qa = 0.f;
  const int xsl = tid & 63;
  const int xkk = (tid >> 6) * 8;
  const int vn  = tid & 127;
  const int vkk = (tid >> 7) * 16;

  for (int kc = 0; kc < DIM; kc += KC) {
    __syncthreads();
#pragma unroll
    for (int m = 0; m < 2; m++) {
      float4 x = *(const float4*)(X + xsl * DIM + kc + xkk + 4 * m);
      Xl[xkk + 4 * m + 0][xsl] = x.x; Xl[xkk + 4 * m + 1][xsl] = x.y;
      Xl[xkk + 4 * m + 2][xsl] = x.z; Xl[xkk + 4 * m + 3][xsl] = x.w;
    }
    {
      int n = n0 + vn;
      bool ok = (n < N_NODES);
      const float* vp = V + (size_t)n * DIM + kc + vkk;
#pragma unroll
      for (int m = 0; m < 4; m++) {
        float4 v = ok ? *(const float4*)(vp + 4 * m) : make_float4(0.f, 0.f, 0.f, 0.f);
        Vl[vkk + 4 * m + 0][vn] = v.x; Vl[vkk + 4 * m + 1][vn] = v.y;
        Vl[vkk + 4 * m + 2][vn] = v.z; Vl[vkk + 4 * m + 3][vn] = v.w;
      }
    }
    __syncthreads();
    if (tid < 128) {
      float qq = 0.f;
#pragma unroll 8
      for (int k = 0; k < KC; k++) { float t = Vl[k][tid]; qq += t * t; }
      qa += qq;
    }
#pragma unroll 4
    for (int k = 0; k < KC; k++) {
      float xs[8], vs[4];
      *(float4*)&xs[0] = *(const float4*)&Xl[k][ty * 8];
      *(float4*)&xs[4] = *(const float4*)&Xl[k][ty * 8 + 4];
      *(float4*)&vs[0] = *(const float4*)&Vl[k][tx * 4];
#pragma unroll
      for (int i = 0; i < 8; i++)
#pragma unroll
        for (int u = 0; u < 4; u++) acc[i][u] += xs[i] * vs[u];
    }
  }
  if (tid < 128) sq[tid] = qa;
  __syncthreads();
  if (tid < 128 && n0 + tid < N_NODES) Q[n0 + tid] = qa;
  float qs[4];
  *(float4*)&qs[0] = *(const float4*)&sq[tx * 4];
  const bool full = (n0 + 128) <= N_NODES;
#pragma unroll
  for (int i = 0; i < 8; i++) {
    int s = ty * 8 + i;
    float xn = XX[s * NS + s];
#pragma unroll
    for (int u = 0; u < 4; u++) acc[i][u] = xn - 2.f * acc[i][u] + qs[u];
    float* prow = P + (size_t)s * N_NODES + n0 + tx * 4;
    if (full) {
      *(float4*)(prow) = make_float4(acc[i][0], acc[i][1], acc[i][2], acc[i][3]);
    } else {
#pragma unroll
      for (int u = 0; u < 4; u++) {
        int n = n0 + tx * 4 + u;
        if (n < N_NODES) prow[u] = acc[i][u];
      }
    }
  }
#pragma unroll
  for (int u = 0; u < 4; u++) {
    int n = n0 + tx * 4 + u;
    if (n < N_NODES) {
      float* pt = PT + (size_t)n * NS + ty * 8;
      *(float4*)(pt)     = make_float4(acc[0][u], acc[1][u], acc[2][u], acc[3][u]);
      *(float4*)(pt + 4) = make_float4(acc[4][u], acc[5][u], acc[6][u], acc[7][u]);
    }
  }
#pragma unroll
  for (int i = 0; i < 8; i++) {
    int s = ty * 8 + i;
    u64 key = ~0ull;
#pragma unroll
    for (int u = 0; u < 4; u++) {
      int n = n0 + tx * 4 + u;
      if (n < N_NODES) key = umin64(key, pk(acc[i][u], n));
    }
#pragma unroll
    for (int off = 1; off <= 8; off <<= 1)
      key = umin64(key, (u64)__shfl_xor((unsigned long long)key, off, 64));
    if ((tx & 15) == 0) {
      int chunk = (n0 >> 6) + (tx >> 4);
      if (chunk < NCH) SUMC[(size_t)s * NCH + chunk] = key;
    }
  }
}

__global__ __launch_bounds__(1024) void k_thresh(const u64* __restrict__ SUMC,
                                                 float* __restrict__ Td,
                                                 int* __restrict__ cnt) {
  __shared__ u64 A[2048];
  const int j = blockIdx.x, tid = threadIdx.x;
  for (int i = tid; i < 2048; i += 1024)
    A[i] = (i < NCH) ? SUMC[(size_t)j * NCH + i] : ~0ull;
  __syncthreads();
  for (int k = 2; k <= 2048; k <<= 1)
    for (int s2 = k >> 1; s2 > 0; s2 >>= 1) {
      for (int i = tid; i < 2048; i += 1024) {
        int p = i ^ s2;
        if (p > i) {
          u64 a = A[i], b = A[p];
          bool up = ((i & k) == 0);
          if ((a > b) == up) { A[i] = b; A[p] = a; }
        }
      }
      __syncthreads();
    }
  if (tid == 0) {
    Td[j] = __uint_as_float((unsigned)(A[159] >> 32));
    cnt[j] = 0;
  }
}

__global__ __launch_bounds__(256) void k_collect(const float* __restrict__ P,
                                                 const float* __restrict__ Td,
                                                 int* __restrict__ cnt,
                                                 u64* __restrict__ cand) {
  const int b = blockIdx.x;
  const int j = b & 63;
  const int seg = b >> 6;
  const int tid = threadIdx.x;
  const int lane = tid & 63;
  const int n0 = seg * 1024 + tid * 4;
  const float T = Td[j];
  const float* prow = P + (size_t)j * N_NODES;
  float d[4];
  if (n0 + 3 < N_NODES) {
    float4 p = *(const float4*)(prow + n0);
    d[0] = p.x; d[1] = p.y; d[2] = p.z; d[3] = p.w;
  } else {
#pragma unroll
    for (int e = 0; e < 4; e++) d[e] = (n0 + e < N_NODES) ? prow[n0 + e] : INFINITY;
  }
#pragma unroll
  for (int e = 0; e < 4; e++) {
    bool hit = (n0 + e < N_NODES) && (d[e] <= T);
    u64 mask = __ballot(hit);
    if (!mask) continue;
    int leader = __ffsll((unsigned long long)mask) - 1;
    int cw = __popcll((unsigned long long)mask);
    int base = 0;
    if (lane == leader) base = atomicAdd(&cnt[j], cw);
    base = __shfl(base, leader, 64);
    if (hit) {
      int pos = base + __popcll((unsigned long long)(mask & ((1ull << lane) - 1)));
      if (pos < CAP) cand[(size_t)j * CAP + pos] = pk(d[e], n0 + e);
    }
  }
}

__global__ __launch_bounds__(256) void k_sort(const int* __restrict__ cnt,
                                              const u64* __restrict__ cand,
                                              u64* __restrict__ L) {
  __shared__ u64 A[4096];
  const int j = blockIdx.x, tid = threadIdx.x;
  int n = cnt[j]; if (n > CAP) n = CAP;
  int M = 256; while (M < n) M <<= 1;
  for (int i = tid; i < M; i += 256)
    A[i] = (i < n) ? cand[(size_t)j * CAP + i] : ~0ull;
  __syncthreads();
  for (int k = 2; k <= M; k <<= 1)
    for (int s2 = k >> 1; s2 > 0; s2 >>= 1) {
      for (int i = tid; i < M; i += 256) {
        int p = i ^ s2;
        if (p > i) {
          u64 a = A[i], b = A[p];
          bool up = ((i & k) == 0);
          if ((a > b) == up) { A[i] = b; A[p] = a; }
        }
      }
      __syncthreads();
    }
  for (int i = tid; i < KL; i += 256) L[(size_t)j * KL + i] = A[i];
}

__global__ __launch_bounds__(128) void k_seq(
    const float* __restrict__ PT, const float* __restrict__ Q,
    const float* __restrict__ XXg, const u64* __restrict__ L,
    const int* __restrict__ itp, float* __restrict__ out) {
  __shared__ float XXl[NS * 65];         // 16.6 KB
  __shared__ float g[128][65];           // 33.3 KB
  __shared__ float qv[128];
  __shared__ unsigned int bitmap[NBMW];  // 12.5 KB (wave-1 scans only)
  __shared__ int tracked[128];
  __shared__ u64 Lbuf[3][KL];            // list ring: wave0 reads j, wave1 scans j+1, loads j+2
  __shared__ u64 verd[3][3];             // tracked-ballot masks per list row
  __shared__ float specg[2][4][NS];      // PT rows of first-4-untracked (double buf)
  __shared__ float specq[2][4];
  __shared__ int   specid[2][4];
  __shared__ float outbuf[NS * 2];

  const int tid = threadIdx.x;           // 128 threads = 2 waves
  const int wv = tid >> 6;
  const int lane = tid & 63;

  // cooperative init
  for (int i4 = tid * 4; i4 < NS * NS; i4 += 128 * 4) {
    int r = i4 >> 6, c = i4 & 63;
    float4 x = *(const float4*)(XXg + i4);
    XXl[r * 65 + c + 0] = x.x; XXl[r * 65 + c + 1] = x.y;
    XXl[r * 65 + c + 2] = x.z; XXl[r * 65 + c + 3] = x.w;
  }
  for (int i = tid; i < NBMW; i += 128) bitmap[i] = 0u;
  for (int i = tid; i < 2 * KL; i += 128) Lbuf[i / KL][i % KL] = L[i];
  __syncthreads();
  // wave-1 prologue: verd[0] + spec[0] (first 4 entries of list 0; bitmap empty)
  if (wv == 1) {
    u64 e0 = Lbuf[0][lane], e1 = Lbuf[0][lane + 64], e2 = Lbuf[0][lane + 128];
    u64 m0 = __ballot(e0 == ~0ull), m1 = __ballot(e1 == ~0ull), m2 = __ballot(e2 == ~0ull);
    if (lane == 0) { verd[0][0] = m0; verd[0][1] = m1; verd[0][2] = m2; }
    int id0 = (int)(unsigned)(Lbuf[0][0] & 0xFFFFFFFFull);
    int id1 = (int)(unsigned)(Lbuf[0][1] & 0xFFFFFFFFull);
    int id2 = (int)(unsigned)(Lbuf[0][2] & 0xFFFFFFFFull);
    int id3 = (int)(unsigned)(Lbuf[0][3] & 0xFFFFFFFFull);
    float p0 = PT[(size_t)id0 * NS + lane], p1 = PT[(size_t)id1 * NS + lane];
    float p2 = PT[(size_t)id2 * NS + lane], p3 = PT[(size_t)id3 * NS + lane];
    specg[0][0][lane] = p0; specg[0][1][lane] = p1;
    specg[0][2][lane] = p2; specg[0][3][lane] = p3;
    if (lane == 0) {
      specid[0][0] = id0; specid[0][1] = id1; specid[0][2] = id2; specid[0][3] = id3;
      specq[0][0] = Q[id0]; specq[0][1] = Q[id1];
      specq[0][2] = Q[id2]; specq[0][3] = Q[id3];
    }
  }
  __syncthreads();

  const int it = itp[0];
  const float eps_b = 1.0f / (float)(it + 2);
  const float eps_n = 1.0f / (float)((it + 1) * 100);
  const float xdl = XXl[lane * 65 + lane];

  int ns = 0, pr0 = -1, pr1 = -1;

  for (int j = 0; j < NS; j++) {
    if (wv == 0) {
      // ===== consumer: pure LDS + VALU =====
      const int rb = j % 3, sb = j & 1;
      u64 k0 = Lbuf[rb][lane], k1 = Lbuf[rb][lane + 64], k2 = Lbuf[rb][lane + 128];
      u64 vm0 = verd[rb][0], vm1 = verd[rb][1], vm2 = verd[rb][2];
      float gA = g[lane][j], gB = g[lane + 64][j];
      float qvA = qv[lane],  qvB = qv[lane + 64];
      int   tA = tracked[lane], tB = tracked[lane + 64];
      float sg0 = specg[sb][0][lane], sg1 = specg[sb][1][lane];
      float sg2 = specg[sb][2][lane], sg3 = specg[sb][3][lane];
      int sid0 = specid[sb][0], sid1 = specid[sb][1];
      int sid2 = specid[sb][2], sid3 = specid[sb][3];
      float sq0 = specq[sb][0], sq1 = specq[sb][1];
      float sq2 = specq[sb][2], sq3 = specq[sb][3];
      float xrow = XXl[j * 65 + lane];
      float xnj = __uint_as_float(
          (unsigned)__builtin_amdgcn_readlane((int)__float_as_uint(xrow), j));
      // verdict-filtered list candidates (patched with previous step's winners)
      u64 A0 = ~0ull, A1 = ~0ull;
      {
        int i0 = (int)(unsigned)(k0 & 0xFFFFFFFFull);
        int i1 = (int)(unsigned)(k1 & 0xFFFFFFFFull);
        int i2 = (int)(unsigned)(k2 & 0xFFFFFFFFull);
        if (!((vm0 >> lane) & 1ull) && i0 != pr0 && i0 != pr1) mrg2(A0, A1, k0, ~0ull);
        if (!((vm1 >> lane) & 1ull) && i1 != pr0 && i1 != pr1) mrg2(A0, A1, k1, ~0ull);
        if (!((vm2 >> lane) & 1ull) && i2 != pr0 && i2 != pr1) mrg2(A0, A1, k2, ~0ull);
      }
      // tracked algebraic distances (expression preserved)
      if (lane < ns)      { float d = xnj - 2.f * gA + qvA; mrg2(A0, A1, pk(d, tA), ~0ull); }
      if (lane + 64 < ns) { float d = xnj - 2.f * gB + qvB; mrg2(A0, A1, pk(d, tB), ~0ull); }
      // DPP min-2 reduction -> exact top-2 in lane 63
      dpp_round<0x111>(A0, A1);
      dpp_round<0x112>(A0, A1);
      dpp_round<0x114>(A0, A1);
      dpp_round<0x118>(A0, A1);
      dpp_round<0x142>(A0, A1);
      dpp_round<0x143>(A0, A1);
      const int r0 = (int)(unsigned)__builtin_amdgcn_readlane(
          (int)(unsigned)(A0 & 0xFFFFFFFFull), 63);
      const int r1 = (int)(unsigned)__builtin_amdgcn_readlane(
          (int)(unsigned)(A1 & 0xFFFFFFFFull), 63);
      if (lane == 63) {
        outbuf[j * 2 + 0] =
            sqrtf(fmaxf(__uint_as_float((unsigned)(A0 >> 32)), 0.f) + 1e-12f);
        outbuf[j * 2 + 1] =
            sqrtf(fmaxf(__uint_as_float((unsigned)(A1 >> 32)), 0.f) + 1e-12f);
      }
      // slot lookup + newness from tracked[] (no bitmap reads)
      bool h0a = (lane < ns) && (tA == r0);
      bool h0b = (lane + 64 < ns) && (tB == r0);
      u64 mk0a = __ballot(h0a), mk0b = __ballot(h0b);
      bool new0 = (mk0a | mk0b) == 0ull;
      int sl0 = new0 ? ns
                     : (mk0a ? (__ffsll((unsigned long long)mk0a) - 1)
                             : (64 + __ffsll((unsigned long long)mk0b) - 1));
      bool h1a = (lane < ns) && (tA == r1);
      bool h1b = (lane + 64 < ns) && (tB == r1);
      u64 mk1a = __ballot(h1a), mk1b = __ballot(h1b);
      bool new1 = (mk1a | mk1b) == 0ull;
      int sl1 = new1 ? (ns + (new0 ? 1 : 0))
                     : (mk1a ? (__ffsll((unsigned long long)mk1a) - 1)
                             : (64 + __ffsll((unsigned long long)mk1b) - 1));
      // spec select (values bitwise identical to direct loads)
      bool m00 = (sid0 == r0), m01 = (sid1 == r0), m02 = (sid2 == r0), m03 = (sid3 == r0);
      bool hit0 = m00 | m01 | m02 | m03;
      float pv0 = m00 ? sg0 : m01 ? sg1 : m02 ? sg2 : sg3;
      float qq0 = m00 ? sq0 : m01 ? sq1 : m02 ? sq2 : sq3;
      bool m10 = (sid0 == r1), m11 = (sid1 == r1), m12 = (sid2 == r1), m13 = (sid3 == r1);
      bool hit1 = m10 | m11 | m12 | m13;
      float pv1 = m10 ? sg0 : m11 ? sg1 : m12 ? sg2 : sg3;
      float qq1 = m10 ? sq0 : m11 ? sq1 : m12 ? sq2 : sq3;
      if (new0 && !hit0) { pv0 = PT[(size_t)r0 * NS + lane]; qq0 = Q[r0]; }  // provably rare/never
      if (new1 && !hit1) { pv1 = PT[(size_t)r1 * NS + lane]; qq1 = Q[r1]; }
      // g-old reads (slots distinct, issued in parallel)
      float gt0 = g[sl0][lane];
      float gt1 = g[sl1][lane];
      // phase 0: r0 / eps_b
      float gold0 = new0 ? (0.5f * (xdl + qq0 - pv0)) : gt0;
      float qold0 = new0 ? qq0
                         : __uint_as_float((unsigned)__builtin_amdgcn_readlane(
                               (int)__float_as_uint(sl0 < 64 ? qvA : qvB), sl0 & 63));
      float gj0 = __uint_as_float(
          (unsigned)__builtin_amdgcn_readlane((int)__float_as_uint(gold0), j));
      g[sl0][lane] = (1.f - eps_b) * gold0 + eps_b * xrow;
      if (lane == 0) {
        float om = 1.f - eps_b;
        qv[sl0] = om * om * qold0 + 2.f * eps_b * om * gj0 + eps_b * eps_b * xnj;
        tracked[sl0] = r0;
        if (new0) bitmap[r0 >> 5] |= 1u << (r0 & 31);
      }
      // phase 1: r1 / eps_n
      float gold1 = new1 ? (0.5f * (xdl + qq1 - pv1)) : gt1;
      float qold1 = new1 ? qq1
                         : __uint_as_float((unsigned)__builtin_amdgcn_readlane(
                               (int)__float_as_uint(sl1 < 64 ? qvA : qvB), sl1 & 63));
      float gj1 = __uint_as_float(
          (unsigned)__builtin_amdgcn_readlane((int)__float_as_uint(gold1), j));
      g[sl1][lane] = (1.f - eps_n) * gold1 + eps_n * xrow;
      if (lane == 0) {
        float on = 1.f - eps_n;
        qv[sl1] = on * on * qold1 + 2.f * eps_n * on * gj1 + eps_n * eps_n * xnj;
        tracked[sl1] = r1;
        if (new1) bitmap[r1 >> 5] |= 1u << (r1 & 31);
      }
      ns += (new0 ? 1 : 0) + (new1 ? 1 : 0);
      pr0 = r0; pr1 = r1;
    } else {
      // ===== producer =====
      if (j + 2 < NS) {  // stage list j+2
        const u64* Lr = L + (size_t)(j + 2) * KL;
        u64 a = Lr[lane], b = Lr[lane + 64], c = Lr[lane + 128];
        int wb = (j + 2) % 3;
        Lbuf[wb][lane] = a; Lbuf[wb][lane + 64] = b; Lbuf[wb][lane + 128] = c;
      }
      if (j + 1 < NS) {  // scan list j+1, prefetch first-4-untracked
        const int rb = (j + 1) % 3, sb2 = (j + 1) & 1;
        u64 e0 = Lbuf[rb][lane], e1 = Lbuf[rb][lane + 64], e2 = Lbuf[rb][lane + 128];
        int i0 = (int)(unsigned)(e0 & 0xFFFFFFFFull);
        int i1 = (int)(unsigned)(e1 & 0xFFFFFFFFull);
        int i2 = (int)(unsigned)(e2 & 0xFFFFFFFFull);
        bool t0 = (e0 == ~0ull) || ((bitmap[i0 >> 5] >> (i0 & 31)) & 1u);
        bool t1 = (e1 == ~0ull) || ((bitmap[i1 >> 5] >> (i1 & 31)) & 1u);
        bool t2 = (e2 == ~0ull) || ((bitmap[i2 >> 5] >> (i2 & 31)) & 1u);
        u64 m0 = __ballot(t0), m1 = __ballot(t1), m2 = __ballot(t2);
        if (lane == 0) { verd[rb][0] = m0; verd[rb][1] = m1; verd[rb][2] = m2; }
        u64 um[3] = {~m0, ~m1, ~m2};
        int posk[4] = {0, 0, 0, 0};
        int pcnt = 0;
#pragma unroll
        for (int gi = 0; gi < 3; gi++) {
          u64 mm = um[gi];
          while (mm && pcnt < 4) {
            int b2 = __ffsll((unsigned long long)mm) - 1;
            posk[pcnt++] = gi * 64 + b2;
            mm &= mm - 1;
          }
        }
        int id0 = (int)(unsigned)(Lbuf[rb][posk[0]] & 0xFFFFFFFFull);
        int id1 = (int)(unsigned)(Lbuf[rb][posk[1]] & 0xFFFFFFFFull);
        int id2 = (int)(unsigned)(Lbuf[rb][posk[2]] & 0xFFFFFFFFull);
        int id3 = (int)(unsigned)(Lbuf[rb][posk[3]] & 0xFFFFFFFFull);
        float p0 = PT[(size_t)id0 * NS + lane], p1 = PT[(size_t)id1 * NS + lane];
        float p2 = PT[(size_t)id2 * NS + lane], p3 = PT[(size_t)id3 * NS + lane];
        specg[sb2][0][lane] = p0; specg[sb2][1][lane] = p1;
        specg[sb2][2][lane] = p2; specg[sb2][3][lane] = p3;
        if (lane == 0) {
          specid[sb2][0] = id0; specid[sb2][1] = id1;
          specid[sb2][2] = id2; specid[sb2][3] = id3;
          specq[sb2][0] = Q[id0]; specq[sb2][1] = Q[id1];
          specq[sb2][2] = Q[id2]; specq[sb2][3] = Q[id3];
        }
      }
    }
    __syncthreads();
  }
  if (tid < NS * 2) out[tid] = outbuf[tid];
}

extern "C" void kernel_launch(void* const* d_in, const int* in_sizes, int n_in,
                              void* d_out, int out_size, void* d_ws, size_t ws_size,
                              hipStream_t stream) {
  const float* X  = (const float*)d_in[0];  // [64,256]
  const float* V  = (const float*)d_in[1];  // [100000,256]
  const int*  itp = (const int*)d_in[3];    // scalar it
  float* out = (float*)d_out;               // [64,2]

  char* ws = (char*)d_ws;
  size_t off = 0;
  auto alloc = [&](size_t bytes) -> void* {
    size_t o = (off + 255) & ~(size_t)255;
    off = o + bytes;
    return (void*)(ws + o);
  };
  float* P    = (float*)alloc((size_t)NS * N_NODES * sizeof(float)); // 25.6 MB
  float* PT   = (float*)alloc((size_t)NS * N_NODES * sizeof(float)); // 25.6 MB
  float* Q    = (float*)alloc((size_t)N_NODES * sizeof(float));
  float* XXp  = (float*)alloc((size_t)NS * NS * sizeof(float));
  u64*   SUMC = (u64*)alloc((size_t)NS * NCH * sizeof(u64));         // 800 KB
  float* Td   = (float*)alloc((size_t)NS * sizeof(float));
  int*   cnt  = (int*)alloc((size_t)NS * sizeof(int));
  u64*   cand = (u64*)alloc((size_t)NS * CAP * sizeof(u64));         // 2 MB
  u64*   Lst  = (u64*)alloc((size_t)NS * KL * sizeof(u64));          // 96 KB

  k_xx     <<<NS, NS, 0, stream>>>(X, XXp);
  k_dist   <<<(N_NODES + 127) / 128, 256, 0, stream>>>(X, V, XXp, P, PT, Q, SUMC);
  k_thresh <<<NS, 1024, 0, stream>>>(SUMC, Td, cnt);
  k_collect<<<64 * 98, 256, 0, stream>>>(P, Td, cnt, cand);
  k_sort   <<<NS, 256, 0, stream>>>(cnt, cand, Lst);
  k_seq    <<<1, 128, 0, stream>>>(PT, Q, XXp, Lst, itp, out);
}

// Round 7
// 340.635 us; speedup vs baseline: 2.3839x; 1.1454x over previous
//
#include <hip/hip_runtime.h>
#include <math.h>

// SOINN+ restructured, round 7:
//  k_xx / k_dist : unchanged from round 6.
//  k_build : fused thresh+collect+sort (64 blocks): T[j]=160th chunk-min (bitonic
//            2048 on SUMC), compact d<=T into LDS, bitonic sort, emit top-192 list.
//  k_seq   : 3 waves, NO per-step barrier.
//    wave 0 (consumer): pure LDS+VALU — verdict-filtered list candidates (patched
//      with previous step's winners), tracked algebraic distances, DPP u64 min-2,
//      ballot slot lookup, g/q updates, bitmap writes, done[j] release-flag.
//    waves 1,2 (producers, alternating t): wait done[t-2], scan LDS list row t vs
//      bitmap -> verdict masks + first-4-untracked PT/Q prefetch, ready[t] release.
//    Coverage: producer state >= winners(0..t-2) => verdict error subset of step
//      t-1 winners (patch-2 exact) and first-4-untracked covers first-2-at-t.
//    All 64 list rows (136 entries each; untracked min-2 provably in top-130)
//    preloaded to LDS once. All value expressions bitwise-identical -> absmax 0.

#define N_NODES 100000
#define DIM     256
#define NS      64
#define NCH     1563
#define KC      32
#define NBMW    3125
#define CAP     4096
#define KL      192
#define KLS     136

typedef unsigned long long u64;

__device__ __forceinline__ u64 pk(float d, int i) {
  return ((u64)__float_as_uint(d) << 32) | (unsigned)i;
}
__device__ __forceinline__ u64 umin64(u64 a, u64 b) { return a < b ? a : b; }
__device__ __forceinline__ u64 umax64(u64 a, u64 b) { return a > b ? a : b; }
__device__ __forceinline__ void mrg2(u64& A0, u64& A1, u64 B0, u64 B1) {
  u64 m = umax64(A0, B0);
  A0 = umin64(A0, B0);
  A1 = umin64(umin64(A1, B1), m);
}

template <int C>
__device__ __forceinline__ u64 dpp64(u64 x) {
  unsigned lo = (unsigned)__builtin_amdgcn_update_dpp(
      (int)0xFFFFFFFF, (int)(unsigned)(x & 0xFFFFFFFFull), C, 0xF, 0xF, false);
  unsigned hi = (unsigned)__builtin_amdgcn_update_dpp(
      (int)0xFFFFFFFF, (int)(unsigned)(x >> 32), C, 0xF, 0xF, false);
  return ((u64)hi << 32) | lo;
}
template <int C>
__device__ __forceinline__ void dpp_round(u64& A0, u64& A1) {
  u64 B0 = dpp64<C>(A0);
  u64 B1 = dpp64<C>(A1);
  mrg2(A0, A1, B0, B1);
}

__global__ void k_xx(const float* __restrict__ X, float* __restrict__ XX) {
  int i = blockIdx.x, j = threadIdx.x;
  const float* xi = X + i * DIM;
  const float* xj = X + j * DIM;
  float acc = 0.f;
  for (int k = 0; k < DIM; k += 4) {
    float4 a = *(const float4*)(xi + k);
    float4 b = *(const float4*)(xj + k);
    acc += a.x * b.x + a.y * b.y + a.z * b.z + a.w * b.w;
  }
  XX[i * NS + j] = acc;
}

__global__ __launch_bounds__(256) void k_dist(const float* __restrict__ X,
                                              const float* __restrict__ V,
                                              const float* __restrict__ XX,
                                              float* __restrict__ P,
                                              float* __restrict__ PT,
                                              float* __restrict__ Q,
                                              u64* __restrict__ SUMC) {
  __shared__ float Xl[KC][68];
  __shared__ float Vl[KC][136];
  __shared__ float sq[128];
  const int tid = threadIdx.x;
  const int n0  = blockIdx.x * 128;
  const int ty  = tid >> 5;
  const int tx  = tid & 31;
  float acc[8][4];
#pragma unroll
  for (int i = 0; i < 8; i++)
#pragma unroll
    for (int u = 0; u < 4; u++) acc[i][u] = 0.f;
  float qa = 0.f;
  const int xsl = tid & 63;
  const int xkk = (tid >> 6) * 8;
  const int vn  = tid & 127;
  const int vkk = (tid >> 7) * 16;

  for (int kc = 0; kc < DIM; kc += KC) {
    __syncthreads();
#pragma unroll
    for (int m = 0; m < 2; m++) {
      float4 x = *(const float4*)(X + xsl * DIM + kc + xkk + 4 * m);
      Xl[xkk + 4 * m + 0][xsl] = x.x; Xl[xkk + 4 * m + 1][xsl] = x.y;
      Xl[xkk + 4 * m + 2][xsl] = x.z; Xl[xkk + 4 * m + 3][xsl] = x.w;
    }
    {
      int n = n0 + vn;
      bool ok = (n < N_NODES);
      const float* vp = V + (size_t)n * DIM + kc + vkk;
#pragma unroll
      for (int m = 0; m < 4; m++) {
        float4 v = ok ? *(const float4*)(vp + 4 * m) : make_float4(0.f, 0.f, 0.f, 0.f);
        Vl[vkk + 4 * m + 0][vn] = v.x; Vl[vkk + 4 * m + 1][vn] = v.y;
        Vl[vkk + 4 * m + 2][vn] = v.z; Vl[vkk + 4 * m + 3][vn] = v.w;
      }
    }
    __syncthreads();
    if (tid < 128) {
      float qq = 0.f;
#pragma unroll 8
      for (int k = 0; k < KC; k++) { float t = Vl[k][tid]; qq += t * t; }
      qa += qq;
    }
#pragma unroll 4
    for (int k = 0; k < KC; k++) {
      float xs[8], vs[4];
      *(float4*)&xs[0] = *(const float4*)&Xl[k][ty * 8];
      *(float4*)&xs[4] = *(const float4*)&Xl[k][ty * 8 + 4];
      *(float4*)&vs[0] = *(const float4*)&Vl[k][tx * 4];
#pragma unroll
      for (int i = 0; i < 8; i++)
#pragma unroll
        for (int u = 0; u < 4; u++) acc[i][u] += xs[i] * vs[u];
    }
  }
  if (tid < 128) sq[tid] = qa;
  __syncthreads();
  if (tid < 128 && n0 + tid < N_NODES) Q[n0 + tid] = qa;
  float qs[4];
  *(float4*)&qs[0] = *(const float4*)&sq[tx * 4];
  const bool full = (n0 + 128) <= N_NODES;
#pragma unroll
  for (int i = 0; i < 8; i++) {
    int s = ty * 8 + i;
    float xn = XX[s * NS + s];
#pragma unroll
    for (int u = 0; u < 4; u++) acc[i][u] = xn - 2.f * acc[i][u] + qs[u];
    float* prow = P + (size_t)s * N_NODES + n0 + tx * 4;
    if (full) {
      *(float4*)(prow) = make_float4(acc[i][0], acc[i][1], acc[i][2], acc[i][3]);
    } else {
#pragma unroll
      for (int u = 0; u < 4; u++) {
        int n = n0 + tx * 4 + u;
        if (n < N_NODES) prow[u] = acc[i][u];
      }
    }
  }
#pragma unroll
  for (int u = 0; u < 4; u++) {
    int n = n0 + tx * 4 + u;
    if (n < N_NODES) {
      float* pt = PT + (size_t)n * NS + ty * 8;
      *(float4*)(pt)     = make_float4(acc[0][u], acc[1][u], acc[2][u], acc[3][u]);
      *(float4*)(pt + 4) = make_float4(acc[4][u], acc[5][u], acc[6][u], acc[7][u]);
    }
  }
#pragma unroll
  for (int i = 0; i < 8; i++) {
    int s = ty * 8 + i;
    u64 key = ~0ull;
#pragma unroll
    for (int u = 0; u < 4; u++) {
      int n = n0 + tx * 4 + u;
      if (n < N_NODES) key = umin64(key, pk(acc[i][u], n));
    }
#pragma unroll
    for (int off = 1; off <= 8; off <<= 1)
      key = umin64(key, (u64)__shfl_xor((unsigned long long)key, off, 64));
    if ((tx & 15) == 0) {
      int chunk = (n0 >> 6) + (tx >> 4);
      if (chunk < NCH) SUMC[(size_t)s * NCH + chunk] = key;
    }
  }
}

// fused threshold + collect + sort: one block per sample
__global__ __launch_bounds__(1024) void k_build(const u64* __restrict__ SUMC,
                                                const float* __restrict__ P,
                                                u64* __restrict__ L) {
  __shared__ u64 A[CAP];            // 32 KB
  __shared__ float Tsh;
  __shared__ int cnt;
  const int j = blockIdx.x, tid = threadIdx.x;
  // phase 1: T = 160th-smallest chunk-min (bitonic over 2048)
  for (int i = tid; i < 2048; i += 1024)
    A[i] = (i < NCH) ? SUMC[(size_t)j * NCH + i] : ~0ull;
  __syncthreads();
  for (int k = 2; k <= 2048; k <<= 1)
    for (int s2 = k >> 1; s2 > 0; s2 >>= 1) {
      for (int i = tid; i < 2048; i += 1024) {
        int p = i ^ s2;
        if (p > i) {
          u64 a = A[i], b = A[p];
          bool up = ((i & k) == 0);
          if ((a > b) == up) { A[i] = b; A[p] = a; }
        }
      }
      __syncthreads();
    }
  if (tid == 0) {
    Tsh = __uint_as_float((unsigned)(A[159] >> 32));
    cnt = 0;
  }
  __syncthreads();
  const float T = Tsh;
  __syncthreads();
  // phase 2: compact candidates (d <= T) into A
  const float* prow = P + (size_t)j * N_NODES;
  for (int n0 = tid * 4; n0 < N_NODES + 3; n0 += 4096) {
    float d[4];
    if (n0 + 3 < N_NODES) {
      float4 p = *(const float4*)(prow + n0);
      d[0] = p.x; d[1] = p.y; d[2] = p.z; d[3] = p.w;
    } else {
#pragma unroll
      for (int e = 0; e < 4; e++)
        d[e] = (n0 + e < N_NODES) ? prow[n0 + e] : INFINITY;
    }
#pragma unroll
    for (int e = 0; e < 4; e++) {
      if (d[e] <= T) {
        int pos = atomicAdd(&cnt, 1);        // compiler wave-aggregates
        if (pos < CAP) A[pos] = pk(d[e], n0 + e);
      }
    }
  }
  __syncthreads();
  int n = cnt; if (n > CAP) n = CAP;
  int M = 256; while (M < n) M <<= 1;
  for (int i = tid; i < M; i += 1024)
    if (i >= n) A[i] = ~0ull;
  __syncthreads();
  // phase 3: bitonic sort M
  for (int k = 2; k <= M; k <<= 1)
    for (int s2 = k >> 1; s2 > 0; s2 >>= 1) {
      for (int i = tid; i < M; i += 1024) {
        int p = i ^ s2;
        if (p > i) {
          u64 a = A[i], b = A[p];
          bool up = ((i & k) == 0);
          if ((a > b) == up) { A[i] = b; A[p] = a; }
        }
      }
      __syncthreads();
    }
  for (int i = tid; i < KL; i += 1024) L[(size_t)j * KL + i] = A[i];
}

__global__ __launch_bounds__(192) void k_seq(
    const float* __restrict__ PT, const float* __restrict__ Q,
    const float* __restrict__ XXg, const u64* __restrict__ L,
    const int* __restrict__ itp, float* __restrict__ out) {
  __shared__ u64 Lsh[NS][KLS];           // 69632 B, static after init
  __shared__ float XXl[NS * 65];         // 16640
  __shared__ float g[128][65];           // 33280
  __shared__ float qv[128];
  __shared__ unsigned int bitmap[NBMW];  // 12500 (wave0 writes, producers read)
  __shared__ int tracked[128];
  __shared__ u64 verd[NS][3];            // 1536
  __shared__ float specg[4][4][NS];      // 4096 (ring by t&3)
  __shared__ float specq[4][4];
  __shared__ int   specid[4][4];
  __shared__ int ready[NS];
  __shared__ int done[NS];

  const int tid = threadIdx.x;           // 192 = 3 waves
  const int wv = tid >> 6;
  const int lane = tid & 63;

  // cooperative init
  for (int i = tid; i < NS * KLS; i += 192) {
    int r = i / KLS, c = i - r * KLS;
    Lsh[r][c] = L[(size_t)r * KL + c];
  }
  for (int i = tid; i < NS * NS; i += 192) {
    int r = i >> 6, c = i & 63;
    XXl[r * 65 + c] = XXg[i];
  }
  for (int i = tid; i < NBMW; i += 192) bitmap[i] = 0u;
  for (int i = tid; i < NS; i += 192) { ready[i] = 0; done[i] = 0; }
  __syncthreads();

  const int it = itp[0];
  const float eps_b = 1.0f / (float)(it + 2);
  const float eps_n = 1.0f / (float)((it + 1) * 100);
  const float xdl = XXl[lane * 65 + lane];

  if (wv == 0) {
    // ================= consumer =================
    int ns = 0, pr0 = -1, pr1 = -1;
    for (int j = 0; j < NS; j++) {
      while (__hip_atomic_load(&ready[j], __ATOMIC_ACQUIRE,
                               __HIP_MEMORY_SCOPE_WORKGROUP) == 0)
        __builtin_amdgcn_s_sleep(1);
      const int sb = j & 3;
      u64 k0 = Lsh[j][lane], k1 = Lsh[j][lane + 64];
      u64 k2 = (lane < 8) ? Lsh[j][128 + lane] : ~0ull;
      u64 vm0 = verd[j][0], vm1 = verd[j][1], vm2 = verd[j][2];
      float gA = g[lane][j], gB = g[lane + 64][j];
      float qvA = qv[lane],  qvB = qv[lane + 64];
      int   tA = tracked[lane], tB = tracked[lane + 64];
      float sg0 = specg[sb][0][lane], sg1 = specg[sb][1][lane];
      float sg2 = specg[sb][2][lane], sg3 = specg[sb][3][lane];
      int sid0 = specid[sb][0], sid1 = specid[sb][1];
      int sid2 = specid[sb][2], sid3 = specid[sb][3];
      float sq0 = specq[sb][0], sq1 = specq[sb][1];
      float sq2 = specq[sb][2], sq3 = specq[sb][3];
      float xrow = XXl[j * 65 + lane];
      float xnj = __uint_as_float(
          (unsigned)__builtin_amdgcn_readlane((int)__float_as_uint(xrow), j));
      // verdict-filtered list candidates, patched with previous step's winners
      u64 A0 = ~0ull, A1 = ~0ull;
      {
        int i0 = (int)(unsigned)(k0 & 0xFFFFFFFFull);
        int i1 = (int)(unsigned)(k1 & 0xFFFFFFFFull);
        int i2 = (int)(unsigned)(k2 & 0xFFFFFFFFull);
        if (!((vm0 >> lane) & 1ull) && i0 != pr0 && i0 != pr1) mrg2(A0, A1, k0, ~0ull);
        if (!((vm1 >> lane) & 1ull) && i1 != pr0 && i1 != pr1) mrg2(A0, A1, k1, ~0ull);
        if (!((vm2 >> lane) & 1ull) && i2 != pr0 && i2 != pr1) mrg2(A0, A1, k2, ~0ull);
      }
      // tracked algebraic distances (expression preserved)
      if (lane < ns)      { float d = xnj - 2.f * gA + qvA; mrg2(A0, A1, pk(d, tA), ~0ull); }
      if (lane + 64 < ns) { float d = xnj - 2.f * gB + qvB; mrg2(A0, A1, pk(d, tB), ~0ull); }
      // DPP min-2 -> exact top-2 in lane 63
      dpp_round<0x111>(A0, A1);
      dpp_round<0x112>(A0, A1);
      dpp_round<0x114>(A0, A1);
      dpp_round<0x118>(A0, A1);
      dpp_round<0x142>(A0, A1);
      dpp_round<0x143>(A0, A1);
      const int r0 = (int)(unsigned)__builtin_amdgcn_readlane(
          (int)(unsigned)(A0 & 0xFFFFFFFFull), 63);
      const int r1 = (int)(unsigned)__builtin_amdgcn_readlane(
          (int)(unsigned)(A1 & 0xFFFFFFFFull), 63);
      if (lane == 63) {
        float2 o;
        o.x = sqrtf(fmaxf(__uint_as_float((unsigned)(A0 >> 32)), 0.f) + 1e-12f);
        o.y = sqrtf(fmaxf(__uint_as_float((unsigned)(A1 >> 32)), 0.f) + 1e-12f);
        *(float2*)(out + j * 2) = o;     // fire-and-forget
      }
      // slot lookup + newness
      bool h0a = (lane < ns) && (tA == r0);
      bool h0b = (lane + 64 < ns) && (tB == r0);
      u64 mk0a = __ballot(h0a), mk0b = __ballot(h0b);
      bool new0 = (mk0a | mk0b) == 0ull;
      int sl0 = new0 ? ns
                     : (mk0a ? (__ffsll((unsigned long long)mk0a) - 1)
                             : (64 + __ffsll((unsigned long long)mk0b) - 1));
      bool h1a = (lane < ns) && (tA == r1);
      bool h1b = (lane + 64 < ns) && (tB == r1);
      u64 mk1a = __ballot(h1a), mk1b = __ballot(h1b);
      bool new1 = (mk1a | mk1b) == 0ull;
      int sl1 = new1 ? (ns + (new0 ? 1 : 0))
                     : (mk1a ? (__ffsll((unsigned long long)mk1a) - 1)
                             : (64 + __ffsll((unsigned long long)mk1b) - 1));
      // spec select (bitwise identical to direct loads; coverage proven)
      bool m00 = (sid0 == r0), m01 = (sid1 == r0), m02 = (sid2 == r0), m03 = (sid3 == r0);
      bool hit0 = m00 | m01 | m02 | m03;
      float pv0 = m00 ? sg0 : m01 ? sg1 : m02 ? sg2 : sg3;
      float qq0 = m00 ? sq0 : m01 ? sq1 : m02 ? sq2 : sq3;
      bool m10 = (sid0 == r1), m11 = (sid1 == r1), m12 = (sid2 == r1), m13 = (sid3 == r1);
      bool hit1 = m10 | m11 | m12 | m13;
      float pv1 = m10 ? sg0 : m11 ? sg1 : m12 ? sg2 : sg3;
      float qq1 = m10 ? sq0 : m11 ? sq1 : m12 ? sq2 : sq3;
      if (new0 && !hit0) { pv0 = PT[(size_t)r0 * NS + lane]; qq0 = Q[r0]; } // never taken
      if (new1 && !hit1) { pv1 = PT[(size_t)r1 * NS + lane]; qq1 = Q[r1]; }
      float gt0 = g[sl0][lane];
      float gt1 = g[sl1][lane];
      // phase 0: r0 / eps_b
      float gold0 = new0 ? (0.5f * (xdl + qq0 - pv0)) : gt0;
      float qold0 = new0 ? qq0
                         : __uint_as_float((unsigned)__builtin_amdgcn_readlane(
                               (int)__float_as_uint(sl0 < 64 ? qvA : qvB), sl0 & 63));
      float gj0 = __uint_as_float(
          (unsigned)__builtin_amdgcn_readlane((int)__float_as_uint(gold0), j));
      g[sl0][lane] = (1.f - eps_b) * gold0 + eps_b * xrow;
      if (lane == 0) {
        float om = 1.f - eps_b;
        qv[sl0] = om * om * qold0 + 2.f * eps_b * om * gj0 + eps_b * eps_b * xnj;
        tracked[sl0] = r0;
        if (new0) bitmap[r0 >> 5] |= 1u << (r0 & 31);
      }
      // phase 1: r1 / eps_n
      float gold1 = new1 ? (0.5f * (xdl + qq1 - pv1)) : gt1;
      float qold1 = new1 ? qq1
                         : __uint_as_float((unsigned)__builtin_amdgcn_readlane(
                               (int)__float_as_uint(sl1 < 64 ? qvA : qvB), sl1 & 63));
      float gj1 = __uint_as_float(
          (unsigned)__builtin_amdgcn_readlane((int)__float_as_uint(gold1), j));
      g[sl1][lane] = (1.f - eps_n) * gold1 + eps_n * xrow;
      if (lane == 0) {
        float on = 1.f - eps_n;
        qv[sl1] = on * on * qold1 + 2.f * eps_n * on * gj1 + eps_n * eps_n * xnj;
        tracked[sl1] = r1;
        if (new1) bitmap[r1 >> 5] |= 1u << (r1 & 31);
      }
      ns += (new0 ? 1 : 0) + (new1 ? 1 : 0);
      pr0 = r0; pr1 = r1;
      __hip_atomic_store(&done[j], 1, __ATOMIC_RELEASE,
                         __HIP_MEMORY_SCOPE_WORKGROUP);
    }
  } else {
    // ================= producers (wv=1: even t, wv=2: odd t) =================
    for (int t = (wv == 1 ? 0 : 1); t < NS; t += 2) {
      if (t >= 2) {
        while (__hip_atomic_load(&done[t - 2], __ATOMIC_ACQUIRE,
                                 __HIP_MEMORY_SCOPE_WORKGROUP) == 0)
          __builtin_amdgcn_s_sleep(1);
      }
      u64 e0 = Lsh[t][lane], e1 = Lsh[t][lane + 64];
      u64 e2 = (lane < 8) ? Lsh[t][128 + lane] : ~0ull;
      int i0 = (int)(unsigned)(e0 & 0xFFFFFFFFull);
      int i1 = (int)(unsigned)(e1 & 0xFFFFFFFFull);
      int i2 = (int)(unsigned)(e2 & 0xFFFFFFFFull);
      bool t0 = (e0 == ~0ull) || ((bitmap[i0 >> 5] >> (i0 & 31)) & 1u);
      bool t1 = (e1 == ~0ull) || ((bitmap[i1 >> 5] >> (i1 & 31)) & 1u);
      bool t2 = (e2 == ~0ull) || ((bitmap[i2 >> 5] >> (i2 & 31)) & 1u);
      u64 m0 = __ballot(t0), m1 = __ballot(t1), m2 = __ballot(t2);
      if (lane == 0) { verd[t][0] = m0; verd[t][1] = m1; verd[t][2] = m2; }
      u64 um[3] = {~m0, ~m1, ~m2};
      int posk[4] = {0, 0, 0, 0};
      int pcnt = 0;
#pragma unroll
      for (int gi = 0; gi < 3; gi++) {
        u64 mm = um[gi];
        while (mm && pcnt < 4) {
          int b2 = __ffsll((unsigned long long)mm) - 1;
          posk[pcnt++] = gi * 64 + b2;
          mm &= mm - 1;
        }
      }
      int id0 = (int)(unsigned)(Lsh[t][posk[0]] & 0xFFFFFFFFull);
      int id1 = (int)(unsigned)(Lsh[t][posk[1]] & 0xFFFFFFFFull);
      int id2 = (int)(unsigned)(Lsh[t][posk[2]] & 0xFFFFFFFFull);
      int id3 = (int)(unsigned)(Lsh[t][posk[3]] & 0xFFFFFFFFull);
      float p0 = PT[(size_t)id0 * NS + lane], p1 = PT[(size_t)id1 * NS + lane];
      float p2 = PT[(size_t)id2 * NS + lane], p3 = PT[(size_t)id3 * NS + lane];
      const int sb = t & 3;
      specg[sb][0][lane] = p0; specg[sb][1][lane] = p1;
      specg[sb][2][lane] = p2; specg[sb][3][lane] = p3;
      if (lane == 0) {
        specid[sb][0] = id0; specid[sb][1] = id1;
        specid[sb][2] = id2; specid[sb][3] = id3;
        specq[sb][0] = Q[id0]; specq[sb][1] = Q[id1];
        specq[sb][2] = Q[id2]; specq[sb][3] = Q[id3];
      }
      __hip_atomic_store(&ready[t], 1, __ATOMIC_RELEASE,
                         __HIP_MEMORY_SCOPE_WORKGROUP);
    }
  }
}

extern "C" void kernel_launch(void* const* d_in, const int* in_sizes, int n_in,
                              void* d_out, int out_size, void* d_ws, size_t ws_size,
                              hipStream_t stream) {
  const float* X  = (const float*)d_in[0];  // [64,256]
  const float* V  = (const float*)d_in[1];  // [100000,256]
  const int*  itp = (const int*)d_in[3];    // scalar it
  float* out = (float*)d_out;               // [64,2]

  char* ws = (char*)d_ws;
  size_t off = 0;
  auto alloc = [&](size_t bytes) -> void* {
    size_t o = (off + 255) & ~(size_t)255;
    off = o + bytes;
    return (void*)(ws + o);
  };
  float* P    = (float*)alloc((size_t)NS * N_NODES * sizeof(float)); // 25.6 MB
  float* PT   = (float*)alloc((size_t)NS * N_NODES * sizeof(float)); // 25.6 MB
  float* Q    = (float*)alloc((size_t)N_NODES * sizeof(float));
  float* XXp  = (float*)alloc((size_t)NS * NS * sizeof(float));
  u64*   SUMC = (u64*)alloc((size_t)NS * NCH * sizeof(u64));         // 800 KB
  u64*   Lst  = (u64*)alloc((size_t)NS * KL * sizeof(u64));          // 96 KB

  k_xx   <<<NS, NS, 0, stream>>>(X, XXp);
  k_dist <<<(N_NODES + 127) / 128, 256, 0, stream>>>(X, V, XXp, P, PT, Q, SUMC);
  k_build<<<NS, 1024, 0, stream>>>(SUMC, P, Lst);
  k_seq  <<<1, 192, 0, stream>>>(PT, Q, XXp, Lst, itp, out);
}

// Round 8
// 316.238 us; speedup vs baseline: 2.5678x; 1.0771x over previous
//
#include <hip/hip_runtime.h>
#include <math.h>

// SOINN+ restructured, round 8:
//  k_xx    : XX[i][j] = x_i . x_j (unchanged).
//  k_dist  : 64x256 tile, 256 thr, 8x8/thread, register-prefetch pipeline.
//            Per-element FMA chains / qa order / epilogue bitwise-identical.
//  k_build : T = max over 16 waves of wave-9th-smallest chunk-min (>=144
//            candidates guaranteed >= 136 needed; smallest-136 list provably
//            unchanged), then collect + bitonic sort + emit top-136.
//  k_seq   : 3 waves, flag-synced (no barriers).
//    consumer (wave 0): pure LDS+VALU; merges 16 producer-compacted untracked
//      candidates (patched vs last-4 winners) + tracked algebraic distances;
//      DPP u64 min-2; ballot slot lookup; g/q updates; done[j] release.
//    producers (waves 1,2; alternating t, wait done[t-3]): read L row t from
//      global, filter vs bitmap, compact first-16-untracked into cand16[t],
//      prefetch PT/Q of first-6-untracked, ready[t] release.
//    Coverage: producer bitmap >= winners(0..t-3); unseen tracked subset of
//      last-4 winners -> patch exact; first-2-untracked-at-t within first-6.

#define N_NODES 100000
#define DIM     256
#define NS      64
#define NCH     1563
#define KC      32
#define NBMW    3125
#define CAP     4096
#define KL      192
#define KLS     136

typedef unsigned long long u64;

__device__ __forceinline__ u64 pk(float d, int i) {
  return ((u64)__float_as_uint(d) << 32) | (unsigned)i;
}
__device__ __forceinline__ u64 umin64(u64 a, u64 b) { return a < b ? a : b; }
__device__ __forceinline__ u64 umax64(u64 a, u64 b) { return a > b ? a : b; }
__device__ __forceinline__ void mrg2(u64& A0, u64& A1, u64 B0, u64 B1) {
  u64 m = umax64(A0, B0);
  A0 = umin64(A0, B0);
  A1 = umin64(umin64(A1, B1), m);
}

template <int C>
__device__ __forceinline__ u64 dpp64(u64 x) {
  unsigned lo = (unsigned)__builtin_amdgcn_update_dpp(
      (int)0xFFFFFFFF, (int)(unsigned)(x & 0xFFFFFFFFull), C, 0xF, 0xF, false);
  unsigned hi = (unsigned)__builtin_amdgcn_update_dpp(
      (int)0xFFFFFFFF, (int)(unsigned)(x >> 32), C, 0xF, 0xF, false);
  return ((u64)hi << 32) | lo;
}
template <int C>
__device__ __forceinline__ void dpp_round(u64& A0, u64& A1) {
  u64 B0 = dpp64<C>(A0);
  u64 B1 = dpp64<C>(A1);
  mrg2(A0, A1, B0, B1);
}

__global__ void k_xx(const float* __restrict__ X, float* __restrict__ XX) {
  int i = blockIdx.x, j = threadIdx.x;
  const float* xi = X + i * DIM;
  const float* xj = X + j * DIM;
  float acc = 0.f;
  for (int k = 0; k < DIM; k += 4) {
    float4 a = *(const float4*)(xi + k);
    float4 b = *(const float4*)(xj + k);
    acc += a.x * b.x + a.y * b.y + a.z * b.z + a.w * b.w;
  }
  XX[i * NS + j] = acc;
}

__global__ __launch_bounds__(256) void k_dist(const float* __restrict__ X,
                                              const float* __restrict__ V,
                                              const float* __restrict__ XX,
                                              float* __restrict__ P,
                                              float* __restrict__ PT,
                                              float* __restrict__ Q,
                                              u64* __restrict__ SUMC) {
  __shared__ float Xl[KC][68];     // 64 samples, k-major
  __shared__ float Vl[KC][264];    // 256 nodes, k-major (+8 pad)
  __shared__ float sq[256];
  const int tid = threadIdx.x;     // 256 threads
  const int n0  = blockIdx.x * 256;
  const int ty  = tid >> 5;        // 0..7  -> samples 8ty..8ty+7
  const int tx  = tid & 31;        // 0..31 -> nodes 8tx..8tx+7
  float acc[8][8];
#pragma unroll
  for (int i = 0; i < 8; i++)
#pragma unroll
    for (int u = 0; u < 8; u++) acc[i][u] = 0.f;
  float qa = 0.f;
  const int xsl = tid & 63;
  const int xkk = (tid >> 6) * 8;
  const int vn  = n0 + tid;
  const bool vok = (vn < N_NODES);
  const float* vrow = V + (size_t)vn * DIM;
  const float* xrow = X + xsl * DIM + xkk;

  float4 xr0, xr1, vr[8];
  // prefetch chunk 0
  xr0 = *(const float4*)(xrow + 0);
  xr1 = *(const float4*)(xrow + 4);
#pragma unroll
  for (int m = 0; m < 8; m++)
    vr[m] = vok ? *(const float4*)(vrow + 4 * m) : make_float4(0.f, 0.f, 0.f, 0.f);

  for (int c = 0; c < 8; c++) {
    __syncthreads();
    // stage regs -> LDS
    Xl[xkk + 0][xsl] = xr0.x; Xl[xkk + 1][xsl] = xr0.y;
    Xl[xkk + 2][xsl] = xr0.z; Xl[xkk + 3][xsl] = xr0.w;
    Xl[xkk + 4][xsl] = xr1.x; Xl[xkk + 5][xsl] = xr1.y;
    Xl[xkk + 6][xsl] = xr1.z; Xl[xkk + 7][xsl] = xr1.w;
#pragma unroll
    for (int m = 0; m < 8; m++) {
      Vl[4 * m + 0][tid] = vr[m].x; Vl[4 * m + 1][tid] = vr[m].y;
      Vl[4 * m + 2][tid] = vr[m].z; Vl[4 * m + 3][tid] = vr[m].w;
    }
    // ||v||^2 chunk partial from regs (k ascending — order preserved)
    {
      float qq = 0.f;
#pragma unroll
      for (int m = 0; m < 8; m++) {
        qq += vr[m].x * vr[m].x; qq += vr[m].y * vr[m].y;
        qq += vr[m].z * vr[m].z; qq += vr[m].w * vr[m].w;
      }
      qa += qq;
    }
    __syncthreads();
    // prefetch next chunk (latency hidden under compute)
    if (c + 1 < 8) {
      int kc = (c + 1) * KC;
      xr0 = *(const float4*)(xrow + kc);
      xr1 = *(const float4*)(xrow + kc + 4);
#pragma unroll
      for (int m = 0; m < 8; m++)
        vr[m] = vok ? *(const float4*)(vrow + kc + 4 * m)
                    : make_float4(0.f, 0.f, 0.f, 0.f);
    }
    // 8x8 FMA, k ascending (per-element chains bitwise preserved)
#pragma unroll 4
    for (int k = 0; k < KC; k++) {
      float xs[8], vs[8];
      *(float4*)&xs[0] = *(const float4*)&Xl[k][ty * 8];
      *(float4*)&xs[4] = *(const float4*)&Xl[k][ty * 8 + 4];
      *(float4*)&vs[0] = *(const float4*)&Vl[k][tx * 8];
      *(float4*)&vs[4] = *(const float4*)&Vl[k][tx * 8 + 4];
#pragma unroll
      for (int i = 0; i < 8; i++)
#pragma unroll
        for (int u = 0; u < 8; u++) acc[i][u] += xs[i] * vs[u];
    }
  }
  sq[tid] = qa;
  __syncthreads();
  if (vok) Q[vn] = qa;
  float qs[8];
  *(float4*)&qs[0] = *(const float4*)&sq[tx * 8];
  *(float4*)&qs[4] = *(const float4*)&sq[tx * 8 + 4];
  const bool full = (n0 + 256) <= N_NODES;
#pragma unroll
  for (int i = 0; i < 8; i++) {
    int s = ty * 8 + i;
    float xn = XX[s * NS + s];
#pragma unroll
    for (int u = 0; u < 8; u++) acc[i][u] = xn - 2.f * acc[i][u] + qs[u];
    float* prow = P + (size_t)s * N_NODES + n0 + tx * 8;
    if (full) {
      *(float4*)(prow)     = make_float4(acc[i][0], acc[i][1], acc[i][2], acc[i][3]);
      *(float4*)(prow + 4) = make_float4(acc[i][4], acc[i][5], acc[i][6], acc[i][7]);
    } else {
#pragma unroll
      for (int u = 0; u < 8; u++) {
        int n = n0 + tx * 8 + u;
        if (n < N_NODES) prow[u] = acc[i][u];
      }
    }
  }
#pragma unroll
  for (int u = 0; u < 8; u++) {
    int n = n0 + tx * 8 + u;
    if (n < N_NODES) {
      float* pt = PT + (size_t)n * NS + ty * 8;
      *(float4*)(pt)     = make_float4(acc[0][u], acc[1][u], acc[2][u], acc[3][u]);
      *(float4*)(pt + 4) = make_float4(acc[4][u], acc[5][u], acc[6][u], acc[7][u]);
    }
  }
  // per-chunk(64) min: 8 threads per chunk
#pragma unroll
  for (int i = 0; i < 8; i++) {
    int s = ty * 8 + i;
    u64 key = ~0ull;
#pragma unroll
    for (int u = 0; u < 8; u++) {
      int n = n0 + tx * 8 + u;
      if (n < N_NODES) key = umin64(key, pk(acc[i][u], n));
    }
#pragma unroll
    for (int off = 1; off <= 4; off <<= 1)
      key = umin64(key, (u64)__shfl_xor((unsigned long long)key, off, 64));
    if ((tx & 7) == 0) {
      int chunk = (n0 >> 6) + (tx >> 3);
      if (chunk < NCH) SUMC[(size_t)s * NCH + chunk] = key;
    }
  }
}

// fused threshold + collect + sort: one block per sample
__global__ __launch_bounds__(1024) void k_build(const u64* __restrict__ SUMC,
                                                const float* __restrict__ P,
                                                u64* __restrict__ L) {
  __shared__ u64 A[CAP];            // 32 KB
  __shared__ u64 Twave[16];
  __shared__ float Tsh;
  __shared__ int cnt;
  const int j = blockIdx.x, tid = threadIdx.x;
  const int w = tid >> 6, l = tid & 63;
  // phase 1: per-wave 9th-smallest chunk-min; T = max over waves.
  // keys are unique (idx in low bits) -> exact single removal per iteration.
  {
    int base = w * 98;
    u64 v0 = (base + l < NCH) ? SUMC[(size_t)j * NCH + base + l] : ~0ull;
    u64 v1 = (l < 34 && base + 64 + l < NCH)
                 ? SUMC[(size_t)j * NCH + base + 64 + l] : ~0ull;
    u64 s9 = ~0ull;
#pragma unroll
    for (int r = 0; r < 9; r++) {
      u64 m = umin64(v0, v1);
#pragma unroll
      for (int off = 1; off <= 32; off <<= 1)
        m = umin64(m, (u64)__shfl_xor((unsigned long long)m, off, 64));
      if (r == 8) { s9 = m; } else {
        if (v0 == m) v0 = ~0ull;
        if (v1 == m) v1 = ~0ull;
      }
    }
    if (l == 0) Twave[w] = s9;
  }
  __syncthreads();
  if (tid == 0) {
    u64 t = 0;
    for (int i = 0; i < 16; i++) t = umax64(t, Twave[i]);
    Tsh = __uint_as_float((unsigned)(t >> 32));   // >=144 entries <= T guaranteed
    cnt = 0;
  }
  __syncthreads();
  const float T = Tsh;
  // phase 2: compact candidates (d <= T) into A
  const float* prow = P + (size_t)j * N_NODES;
  for (int n0 = tid * 4; n0 < N_NODES + 3; n0 += 4096) {
    float d[4];
    if (n0 + 3 < N_NODES) {
      float4 p = *(const float4*)(prow + n0);
      d[0] = p.x; d[1] = p.y; d[2] = p.z; d[3] = p.w;
    } else {
#pragma unroll
      for (int e = 0; e < 4; e++)
        d[e] = (n0 + e < N_NODES) ? prow[n0 + e] : INFINITY;
    }
#pragma unroll
    for (int e = 0; e < 4; e++) {
      if (d[e] <= T) {
        int pos = atomicAdd(&cnt, 1);
        if (pos < CAP) A[pos] = pk(d[e], n0 + e);
      }
    }
  }
  __syncthreads();
  int n = cnt; if (n > CAP) n = CAP;
  int M = 256; while (M < n) M <<= 1;
  for (int i = tid; i < M; i += 1024)
    if (i >= n) A[i] = ~0ull;
  __syncthreads();
  // phase 3: bitonic sort M
  for (int k = 2; k <= M; k <<= 1)
    for (int s2 = k >> 1; s2 > 0; s2 >>= 1) {
      for (int i = tid; i < M; i += 1024) {
        int p = i ^ s2;
        if (p > i) {
          u64 a = A[i], b = A[p];
          bool up = ((i & k) == 0);
          if ((a > b) == up) { A[i] = b; A[p] = a; }
        }
      }
      __syncthreads();
    }
  for (int i = tid; i < KLS; i += 1024) L[(size_t)j * KL + i] = A[i];
}

__global__ __launch_bounds__(192) void k_seq(
    const float* __restrict__ PT, const float* __restrict__ Q,
    const float* __restrict__ XXg, const u64* __restrict__ L,
    const int* __restrict__ itp, float* __restrict__ out) {
  __shared__ float XXl[NS * 65];         // 16640
  __shared__ float g[128][65];           // 33280
  __shared__ float qv[128];
  __shared__ unsigned int bitmap[NBMW];  // 12500 (wave0 writes, producers read)
  __shared__ int tracked[128];
  __shared__ u64 cand16[NS][16];         // 8192: first-16-untracked per step
  __shared__ float specg[4][6][NS];      // 6144: PT rows of first-6-untracked
  __shared__ float specq[4][6];
  __shared__ int   specid[4][6];
  __shared__ int ready[NS];
  __shared__ int done[NS];

  const int tid = threadIdx.x;           // 192 = 3 waves
  const int wv = tid >> 6;
  const int lane = tid & 63;

  for (int i = tid; i < NS * NS; i += 192) {
    int r = i >> 6, c = i & 63;
    XXl[r * 65 + c] = XXg[i];
  }
  for (int i = tid; i < NBMW; i += 192) bitmap[i] = 0u;
  for (int i = tid; i < NS; i += 192) { ready[i] = 0; done[i] = 0; }
  __syncthreads();

  const int it = itp[0];
  const float eps_b = 1.0f / (float)(it + 2);
  const float eps_n = 1.0f / (float)((it + 1) * 100);
  const float xdl = XXl[lane * 65 + lane];

  if (wv == 0) {
    // ================= consumer: pure LDS + VALU =================
    int ns = 0;
    int pw0 = -1, pw1 = -1, pw2 = -1, pw3 = -1;   // winners of steps j-1, j-2
    for (int j = 0; j < NS; j++) {
      while (__hip_atomic_load(&ready[j], __ATOMIC_ACQUIRE,
                               __HIP_MEMORY_SCOPE_WORKGROUP) == 0)
        __builtin_amdgcn_s_sleep(1);
      const int sb = j & 3;
      u64 ck = (lane < 16) ? cand16[j][lane] : ~0ull;
      float sgv[6], sqv[6]; int sid[6];
#pragma unroll
      for (int s = 0; s < 6; s++) {
        sgv[s] = specg[sb][s][lane];
        sid[s] = specid[sb][s];
        sqv[s] = specq[sb][s];
      }
      float gA = g[lane][j], gB = g[lane + 64][j];
      float qvA = qv[lane],  qvB = qv[lane + 64];
      int   tA = tracked[lane], tB = tracked[lane + 64];
      float xrow = XXl[j * 65 + lane];
      float xnj  = XXl[j * 65 + j];
      // candidates: compacted untracked list entry (patched vs last-4 winners)
      u64 A0 = ~0ull, A1 = ~0ull;
      {
        int id = (int)(unsigned)(ck & 0xFFFFFFFFull);
        bool ok = (ck != ~0ull) && id != pw0 && id != pw1 && id != pw2 && id != pw3;
        if (ok) { A0 = ck; }
      }
      // tracked algebraic distances (expression preserved)
      if (lane < ns)      { float d = xnj - 2.f * gA + qvA; mrg2(A0, A1, pk(d, tA), ~0ull); }
      if (lane + 64 < ns) { float d = xnj - 2.f * gB + qvB; mrg2(A0, A1, pk(d, tB), ~0ull); }
      // DPP min-2 -> exact top-2 in lane 63
      dpp_round<0x111>(A0, A1);
      dpp_round<0x112>(A0, A1);
      dpp_round<0x114>(A0, A1);
      dpp_round<0x118>(A0, A1);
      dpp_round<0x142>(A0, A1);
      dpp_round<0x143>(A0, A1);
      const int r0 = (int)(unsigned)__builtin_amdgcn_readlane(
          (int)(unsigned)(A0 & 0xFFFFFFFFull), 63);
      const int r1 = (int)(unsigned)__builtin_amdgcn_readlane(
          (int)(unsigned)(A1 & 0xFFFFFFFFull), 63);
      if (lane == 63) {
        float2 o;
        o.x = sqrtf(fmaxf(__uint_as_float((unsigned)(A0 >> 32)), 0.f) + 1e-12f);
        o.y = sqrtf(fmaxf(__uint_as_float((unsigned)(A1 >> 32)), 0.f) + 1e-12f);
        *(float2*)(out + j * 2) = o;
      }
      // slot lookup + newness
      bool h0a = (lane < ns) && (tA == r0);
      bool h0b = (lane + 64 < ns) && (tB == r0);
      u64 mk0a = __ballot(h0a), mk0b = __ballot(h0b);
      bool new0 = (mk0a | mk0b) == 0ull;
      int sl0 = new0 ? ns
                     : (mk0a ? (__ffsll((unsigned long long)mk0a) - 1)
                             : (64 + __ffsll((unsigned long long)mk0b) - 1));
      bool h1a = (lane < ns) && (tA == r1);
      bool h1b = (lane + 64 < ns) && (tB == r1);
      u64 mk1a = __ballot(h1a), mk1b = __ballot(h1b);
      bool new1 = (mk1a | mk1b) == 0ull;
      int sl1 = new1 ? (ns + (new0 ? 1 : 0))
                     : (mk1a ? (__ffsll((unsigned long long)mk1a) - 1)
                             : (64 + __ffsll((unsigned long long)mk1b) - 1));
      // spec select over 6 (values bitwise identical to direct loads)
      bool hit0 = false, hit1 = false;
      float pv0 = 0.f, qq0 = 0.f, pv1 = 0.f, qq1 = 0.f;
#pragma unroll
      for (int s = 0; s < 6; s++) {
        bool h0 = (sid[s] == r0), h1 = (sid[s] == r1);
        pv0 = h0 ? sgv[s] : pv0;  qq0 = h0 ? sqv[s] : qq0;  hit0 |= h0;
        pv1 = h1 ? sgv[s] : pv1;  qq1 = h1 ? sqv[s] : qq1;  hit1 |= h1;
      }
      if (new0 && !hit0) { pv0 = PT[(size_t)r0 * NS + lane]; qq0 = Q[r0]; } // never taken
      if (new1 && !hit1) { pv1 = PT[(size_t)r1 * NS + lane]; qq1 = Q[r1]; }
      float gt0 = g[sl0][lane];
      float gt1 = g[sl1][lane];
      // phase 0: r0 / eps_b
      float gold0 = new0 ? (0.5f * (xdl + qq0 - pv0)) : gt0;
      float qold0 = new0 ? qq0
                         : __uint_as_float((unsigned)__builtin_amdgcn_readlane(
                               (int)__float_as_uint(sl0 < 64 ? qvA : qvB), sl0 & 63));
      float gj0 = __uint_as_float(
          (unsigned)__builtin_amdgcn_readlane((int)__float_as_uint(gold0), j));
      g[sl0][lane] = (1.f - eps_b) * gold0 + eps_b * xrow;
      if (lane == 0) {
        float om = 1.f - eps_b;
        qv[sl0] = om * om * qold0 + 2.f * eps_b * om * gj0 + eps_b * eps_b * xnj;
        tracked[sl0] = r0;
        if (new0) bitmap[r0 >> 5] |= 1u << (r0 & 31);
      }
      // phase 1: r1 / eps_n
      float gold1 = new1 ? (0.5f * (xdl + qq1 - pv1)) : gt1;
      float qold1 = new1 ? qq1
                         : __uint_as_float((unsigned)__builtin_amdgcn_readlane(
                               (int)__float_as_uint(sl1 < 64 ? qvA : qvB), sl1 & 63));
      float gj1 = __uint_as_float(
          (unsigned)__builtin_amdgcn_readlane((int)__float_as_uint(gold1), j));
      g[sl1][lane] = (1.f - eps_n) * gold1 + eps_n * xrow;
      if (lane == 0) {
        float on = 1.f - eps_n;
        qv[sl1] = on * on * qold1 + 2.f * eps_n * on * gj1 + eps_n * eps_n * xnj;
        tracked[sl1] = r1;
        if (new1) bitmap[r1 >> 5] |= 1u << (r1 & 31);
      }
      ns += (new0 ? 1 : 0) + (new1 ? 1 : 0);
      pw2 = pw0; pw3 = pw1; pw0 = r0; pw1 = r1;
      __hip_atomic_store(&done[j], 1, __ATOMIC_RELEASE,
                         __HIP_MEMORY_SCOPE_WORKGROUP);
    }
  } else {
    // ========== producers (wv=1: even t, wv=2: odd t), wait done[t-3] ==========
    for (int t = (wv == 1 ? 0 : 1); t < NS; t += 2) {
      if (t >= 3) {
        while (__hip_atomic_load(&done[t - 3], __ATOMIC_ACQUIRE,
                                 __HIP_MEMORY_SCOPE_WORKGROUP) == 0)
          __builtin_amdgcn_s_sleep(1);
      }
      const u64* Lr = L + (size_t)t * KL;
      u64 e0 = Lr[lane], e1 = Lr[lane + 64];
      u64 e2 = (lane < 8) ? Lr[128 + lane] : ~0ull;
      int i0 = (int)(unsigned)(e0 & 0xFFFFFFFFull);
      int i1 = (int)(unsigned)(e1 & 0xFFFFFFFFull);
      int i2 = (int)(unsigned)(e2 & 0xFFFFFFFFull);
      bool t0 = (e0 == ~0ull) || ((bitmap[i0 >> 5] >> (i0 & 31)) & 1u);
      bool t1 = (e1 == ~0ull) || ((bitmap[i1 >> 5] >> (i1 & 31)) & 1u);
      bool t2 = (e2 == ~0ull) || ((bitmap[i2 >> 5] >> (i2 & 31)) & 1u);
      u64 um0 = ~__ballot(t0), um1 = ~__ballot(t1), um2 = ~__ballot(t2);
      u64 below = (1ull << lane) - 1;
      int c0n = __popcll((unsigned long long)um0);
      int c1n = __popcll((unsigned long long)um1);
      int rank0 = __popcll((unsigned long long)(um0 & below));
      int rank1 = c0n + __popcll((unsigned long long)(um1 & below));
      int rank2 = c0n + c1n + __popcll((unsigned long long)(um2 & below));
      if (!t0 && rank0 < 16) cand16[t][rank0] = e0;
      if (!t1 && rank1 < 16) cand16[t][rank1] = e1;
      if (!t2 && rank2 < 16) cand16[t][rank2] = e2;
      int U = c0n + c1n + __popcll((unsigned long long)um2);
      if (lane < 16 && lane >= U) cand16[t][lane] = ~0ull;
      // spec: first-6-untracked PT/Q (U >= 136-126 = 10 >= 6 always)
      const int sb = t & 3;
      int ids[6];
#pragma unroll
      for (int s = 0; s < 6; s++)
        ids[s] = (int)(unsigned)(cand16[t][s] & 0xFFFFFFFFull);
#pragma unroll
      for (int s = 0; s < 6; s++)
        specg[sb][s][lane] = PT[(size_t)ids[s] * NS + lane];
      if (lane < 6) {
        specid[sb][lane] = ids[lane];
        specq[sb][lane] = Q[ids[lane]];
      }
      __hip_atomic_store(&ready[t], 1, __ATOMIC_RELEASE,
                         __HIP_MEMORY_SCOPE_WORKGROUP);
    }
  }
}

extern "C" void kernel_launch(void* const* d_in, const int* in_sizes, int n_in,
                              void* d_out, int out_size, void* d_ws, size_t ws_size,
                              hipStream_t stream) {
  const float* X  = (const float*)d_in[0];  // [64,256]
  const float* V  = (const float*)d_in[1];  // [100000,256]
  const int*  itp = (const int*)d_in[3];    // scalar it
  float* out = (float*)d_out;               // [64,2]

  char* ws = (char*)d_ws;
  size_t off = 0;
  auto alloc = [&](size_t bytes) -> void* {
    size_t o = (off + 255) & ~(size_t)255;
    off = o + bytes;
    return (void*)(ws + o);
  };
  float* P    = (float*)alloc((size_t)NS * N_NODES * sizeof(float)); // 25.6 MB
  float* PT   = (float*)alloc((size_t)NS * N_NODES * sizeof(float)); // 25.6 MB
  float* Q    = (float*)alloc((size_t)N_NODES * sizeof(float));
  float* XXp  = (float*)alloc((size_t)NS * NS * sizeof(float));
  u64*   SUMC = (u64*)alloc((size_t)NS * NCH * sizeof(u64));         // 800 KB
  u64*   Lst  = (u64*)alloc((size_t)NS * KL * sizeof(u64));          // 96 KB

  k_xx   <<<NS, NS, 0, stream>>>(X, XXp);
  k_dist <<<(N_NODES + 255) / 256, 256, 0, stream>>>(X, V, XXp, P, PT, Q, SUMC);
  k_build<<<NS, 1024, 0, stream>>>(SUMC, P, Lst);
  k_seq  <<<1, 192, 0, stream>>>(PT, Q, XXp, Lst, itp, out);
}

// Round 9
// 308.279 us; speedup vs baseline: 2.6341x; 1.0258x over previous
//
#include <hip/hip_runtime.h>
#include <math.h>

// SOINN+ restructured, round 9:
//  k_xx    : unchanged.
//  k_dist  : 128-node tile (782 blocks -> 3 blocks/CU), 256 thr, 8x4/thread.
//            Stride-4 b128 V reads = bank-optimal (all 32 banks, HW minimum).
//            Register-prefetch pipeline from R8. FMA/qa/epilogue/SUMC chains
//            bitwise-identical to the verified R5 kernel.
//  k_build : unchanged from round 8.
//  k_seq   : unchanged from round 8 (flag-synced producer/consumer).

#define N_NODES 100000
#define DIM     256
#define NS      64
#define NCH     1563
#define KC      32
#define NBMW    3125
#define CAP     4096
#define KL      192
#define KLS     136

typedef unsigned long long u64;

__device__ __forceinline__ u64 pk(float d, int i) {
  return ((u64)__float_as_uint(d) << 32) | (unsigned)i;
}
__device__ __forceinline__ u64 umin64(u64 a, u64 b) { return a < b ? a : b; }
__device__ __forceinline__ u64 umax64(u64 a, u64 b) { return a > b ? a : b; }
__device__ __forceinline__ void mrg2(u64& A0, u64& A1, u64 B0, u64 B1) {
  u64 m = umax64(A0, B0);
  A0 = umin64(A0, B0);
  A1 = umin64(umin64(A1, B1), m);
}

template <int C>
__device__ __forceinline__ u64 dpp64(u64 x) {
  unsigned lo = (unsigned)__builtin_amdgcn_update_dpp(
      (int)0xFFFFFFFF, (int)(unsigned)(x & 0xFFFFFFFFull), C, 0xF, 0xF, false);
  unsigned hi = (unsigned)__builtin_amdgcn_update_dpp(
      (int)0xFFFFFFFF, (int)(unsigned)(x >> 32), C, 0xF, 0xF, false);
  return ((u64)hi << 32) | lo;
}
template <int C>
__device__ __forceinline__ void dpp_round(u64& A0, u64& A1) {
  u64 B0 = dpp64<C>(A0);
  u64 B1 = dpp64<C>(A1);
  mrg2(A0, A1, B0, B1);
}

__global__ void k_xx(const float* __restrict__ X, float* __restrict__ XX) {
  int i = blockIdx.x, j = threadIdx.x;
  const float* xi = X + i * DIM;
  const float* xj = X + j * DIM;
  float acc = 0.f;
  for (int k = 0; k < DIM; k += 4) {
    float4 a = *(const float4*)(xi + k);
    float4 b = *(const float4*)(xj + k);
    acc += a.x * b.x + a.y * b.y + a.z * b.z + a.w * b.w;
  }
  XX[i * NS + j] = acc;
}

__global__ __launch_bounds__(256) void k_dist(const float* __restrict__ X,
                                              const float* __restrict__ V,
                                              const float* __restrict__ XX,
                                              float* __restrict__ P,
                                              float* __restrict__ PT,
                                              float* __restrict__ Q,
                                              u64* __restrict__ SUMC) {
  __shared__ float Xl[KC][68];     // 64 samples, k-major
  __shared__ float Vl[KC][132];    // 128 nodes, k-major (+4 pad; rows 16B-aligned)
  __shared__ float sq[128];
  const int tid = threadIdx.x;     // 256 threads
  const int n0  = blockIdx.x * 128;
  const int ty  = tid >> 5;        // 0..7  -> samples 8ty..8ty+7
  const int tx  = tid & 31;        // 0..31 -> nodes 4tx..4tx+3 (stride-4: bank-optimal)
  float acc[8][4];
#pragma unroll
  for (int i = 0; i < 8; i++)
#pragma unroll
    for (int u = 0; u < 4; u++) acc[i][u] = 0.f;
  float qa = 0.f;
  const int xsl = tid & 63;            // sample row for X staging
  const int xkk = (tid >> 6) * 8;      // 4 wave-groups cover k-offsets 0,8,16,24
  const int vn  = tid & 127;           // node for V staging
  const int vkk = (tid >> 7) * 16;     // 2 half-grids cover k-offsets 0,16
  const bool vok = (n0 + vn < N_NODES);
  const float* vrow = V + (size_t)(n0 + vn) * DIM + vkk;
  const float* xrow = X + xsl * DIM + xkk;

  float4 xr0, xr1, vr[4];
  // prefetch chunk 0
  xr0 = *(const float4*)(xrow + 0);
  xr1 = *(const float4*)(xrow + 4);
#pragma unroll
  for (int m = 0; m < 4; m++)
    vr[m] = vok ? *(const float4*)(vrow + 4 * m) : make_float4(0.f, 0.f, 0.f, 0.f);

  for (int c = 0; c < 8; c++) {
    __syncthreads();
    // stage regs -> LDS (X transposed k-major; V half-chunk per thread)
    Xl[xkk + 0][xsl] = xr0.x; Xl[xkk + 1][xsl] = xr0.y;
    Xl[xkk + 2][xsl] = xr0.z; Xl[xkk + 3][xsl] = xr0.w;
    Xl[xkk + 4][xsl] = xr1.x; Xl[xkk + 5][xsl] = xr1.y;
    Xl[xkk + 6][xsl] = xr1.z; Xl[xkk + 7][xsl] = xr1.w;
#pragma unroll
    for (int m = 0; m < 4; m++) {
      Vl[vkk + 4 * m + 0][vn] = vr[m].x; Vl[vkk + 4 * m + 1][vn] = vr[m].y;
      Vl[vkk + 4 * m + 2][vn] = vr[m].z; Vl[vkk + 4 * m + 3][vn] = vr[m].w;
    }
    __syncthreads();
    // prefetch next chunk (latency hides under qa + FMA below)
    if (c + 1 < 8) {
      int kc = (c + 1) * KC;
      xr0 = *(const float4*)(xrow + kc);
      xr1 = *(const float4*)(xrow + kc + 4);
#pragma unroll
      for (int m = 0; m < 4; m++)
        vr[m] = vok ? *(const float4*)(vrow + kc + 4 * m)
                    : make_float4(0.f, 0.f, 0.f, 0.f);
    }
    // ||v||^2 chunk partial — node n0+tid, k ascending (bitwise chain of R5)
    if (tid < 128) {
      float qq = 0.f;
#pragma unroll 8
      for (int k = 0; k < KC; k++) { float t = Vl[k][tid]; qq += t * t; }
      qa += qq;
    }
    // 8x4 register-tile FMA, k ascending (per-element chains bitwise preserved)
#pragma unroll 4
    for (int k = 0; k < KC; k++) {
      float xs[8], vs[4];
      *(float4*)&xs[0] = *(const float4*)&Xl[k][ty * 8];      // broadcast (free)
      *(float4*)&xs[4] = *(const float4*)&Xl[k][ty * 8 + 4];  // broadcast (free)
      *(float4*)&vs[0] = *(const float4*)&Vl[k][tx * 4];      // stride-4: bank-optimal
#pragma unroll
      for (int i = 0; i < 8; i++)
#pragma unroll
        for (int u = 0; u < 4; u++) acc[i][u] += xs[i] * vs[u];
    }
  }
  if (tid < 128) sq[tid] = qa;
  __syncthreads();
  if (tid < 128 && n0 + tid < N_NODES) Q[n0 + tid] = qa;
  float qs[4];
  *(float4*)&qs[0] = *(const float4*)&sq[tx * 4];
  const bool full = (n0 + 128) <= N_NODES;
#pragma unroll
  for (int i = 0; i < 8; i++) {
    int s = ty * 8 + i;
    float xn = XX[s * NS + s];
#pragma unroll
    for (int u = 0; u < 4; u++) acc[i][u] = xn - 2.f * acc[i][u] + qs[u];
    float* prow = P + (size_t)s * N_NODES + n0 + tx * 4;
    if (full) {
      *(float4*)(prow) = make_float4(acc[i][0], acc[i][1], acc[i][2], acc[i][3]);
    } else {
#pragma unroll
      for (int u = 0; u < 4; u++) {
        int n = n0 + tx * 4 + u;
        if (n < N_NODES) prow[u] = acc[i][u];
      }
    }
  }
#pragma unroll
  for (int u = 0; u < 4; u++) {
    int n = n0 + tx * 4 + u;
    if (n < N_NODES) {
      float* pt = PT + (size_t)n * NS + ty * 8;
      *(float4*)(pt)     = make_float4(acc[0][u], acc[1][u], acc[2][u], acc[3][u]);
      *(float4*)(pt + 4) = make_float4(acc[4][u], acc[5][u], acc[6][u], acc[7][u]);
    }
  }
  // fused per-chunk(64) min: 16 tx-lanes per chunk (verified R5 form)
#pragma unroll
  for (int i = 0; i < 8; i++) {
    int s = ty * 8 + i;
    u64 key = ~0ull;
#pragma unroll
    for (int u = 0; u < 4; u++) {
      int n = n0 + tx * 4 + u;
      if (n < N_NODES) key = umin64(key, pk(acc[i][u], n));
    }
#pragma unroll
    for (int off = 1; off <= 8; off <<= 1)
      key = umin64(key, (u64)__shfl_xor((unsigned long long)key, off, 64));
    if ((tx & 15) == 0) {
      int chunk = (n0 >> 6) + (tx >> 4);
      if (chunk < NCH) SUMC[(size_t)s * NCH + chunk] = key;
    }
  }
}

// fused threshold + collect + sort: one block per sample
__global__ __launch_bounds__(1024) void k_build(const u64* __restrict__ SUMC,
                                                const float* __restrict__ P,
                                                u64* __restrict__ L) {
  __shared__ u64 A[CAP];            // 32 KB
  __shared__ u64 Twave[16];
  __shared__ float Tsh;
  __shared__ int cnt;
  const int j = blockIdx.x, tid = threadIdx.x;
  const int w = tid >> 6, l = tid & 63;
  // phase 1: per-wave 9th-smallest chunk-min; T = max over waves.
  {
    int base = w * 98;
    u64 v0 = (base + l < NCH) ? SUMC[(size_t)j * NCH + base + l] : ~0ull;
    u64 v1 = (l < 34 && base + 64 + l < NCH)
                 ? SUMC[(size_t)j * NCH + base + 64 + l] : ~0ull;
    u64 s9 = ~0ull;
#pragma unroll
    for (int r = 0; r < 9; r++) {
      u64 m = umin64(v0, v1);
#pragma unroll
      for (int off = 1; off <= 32; off <<= 1)
        m = umin64(m, (u64)__shfl_xor((unsigned long long)m, off, 64));
      if (r == 8) { s9 = m; } else {
        if (v0 == m) v0 = ~0ull;
        if (v1 == m) v1 = ~0ull;
      }
    }
    if (l == 0) Twave[w] = s9;
  }
  __syncthreads();
  if (tid == 0) {
    u64 t = 0;
    for (int i = 0; i < 16; i++) t = umax64(t, Twave[i]);
    Tsh = __uint_as_float((unsigned)(t >> 32));   // >=144 entries <= T guaranteed
    cnt = 0;
  }
  __syncthreads();
  const float T = Tsh;
  // phase 2: compact candidates (d <= T) into A
  const float* prow = P + (size_t)j * N_NODES;
  for (int n0 = tid * 4; n0 < N_NODES + 3; n0 += 4096) {
    float d[4];
    if (n0 + 3 < N_NODES) {
      float4 p = *(const float4*)(prow + n0);
      d[0] = p.x; d[1] = p.y; d[2] = p.z; d[3] = p.w;
    } else {
#pragma unroll
      for (int e = 0; e < 4; e++)
        d[e] = (n0 + e < N_NODES) ? prow[n0 + e] : INFINITY;
    }
#pragma unroll
    for (int e = 0; e < 4; e++) {
      if (d[e] <= T) {
        int pos = atomicAdd(&cnt, 1);
        if (pos < CAP) A[pos] = pk(d[e], n0 + e);
      }
    }
  }
  __syncthreads();
  int n = cnt; if (n > CAP) n = CAP;
  int M = 256; while (M < n) M <<= 1;
  for (int i = tid; i < M; i += 1024)
    if (i >= n) A[i] = ~0ull;
  __syncthreads();
  // phase 3: bitonic sort M
  for (int k = 2; k <= M; k <<= 1)
    for (int s2 = k >> 1; s2 > 0; s2 >>= 1) {
      for (int i = tid; i < M; i += 1024) {
        int p = i ^ s2;
        if (p > i) {
          u64 a = A[i], b = A[p];
          bool up = ((i & k) == 0);
          if ((a > b) == up) { A[i] = b; A[p] = a; }
        }
      }
      __syncthreads();
    }
  for (int i = tid; i < KLS; i += 1024) L[(size_t)j * KL + i] = A[i];
}

__global__ __launch_bounds__(192) void k_seq(
    const float* __restrict__ PT, const float* __restrict__ Q,
    const float* __restrict__ XXg, const u64* __restrict__ L,
    const int* __restrict__ itp, float* __restrict__ out) {
  __shared__ float XXl[NS * 65];         // 16640
  __shared__ float g[128][65];           // 33280
  __shared__ float qv[128];
  __shared__ unsigned int bitmap[NBMW];  // 12500 (wave0 writes, producers read)
  __shared__ int tracked[128];
  __shared__ u64 cand16[NS][16];         // 8192: first-16-untracked per step
  __shared__ float specg[4][6][NS];      // 6144: PT rows of first-6-untracked
  __shared__ float specq[4][6];
  __shared__ int   specid[4][6];
  __shared__ int ready[NS];
  __shared__ int done[NS];

  const int tid = threadIdx.x;           // 192 = 3 waves
  const int wv = tid >> 6;
  const int lane = tid & 63;

  for (int i = tid; i < NS * NS; i += 192) {
    int r = i >> 6, c = i & 63;
    XXl[r * 65 + c] = XXg[i];
  }
  for (int i = tid; i < NBMW; i += 192) bitmap[i] = 0u;
  for (int i = tid; i < NS; i += 192) { ready[i] = 0; done[i] = 0; }
  __syncthreads();

  const int it = itp[0];
  const float eps_b = 1.0f / (float)(it + 2);
  const float eps_n = 1.0f / (float)((it + 1) * 100);
  const float xdl = XXl[lane * 65 + lane];

  if (wv == 0) {
    // ================= consumer: pure LDS + VALU =================
    int ns = 0;
    int pw0 = -1, pw1 = -1, pw2 = -1, pw3 = -1;   // winners of steps j-1, j-2
    for (int j = 0; j < NS; j++) {
      while (__hip_atomic_load(&ready[j], __ATOMIC_ACQUIRE,
                               __HIP_MEMORY_SCOPE_WORKGROUP) == 0)
        __builtin_amdgcn_s_sleep(1);
      const int sb = j & 3;
      u64 ck = (lane < 16) ? cand16[j][lane] : ~0ull;
      float sgv[6], sqv[6]; int sid[6];
#pragma unroll
      for (int s = 0; s < 6; s++) {
        sgv[s] = specg[sb][s][lane];
        sid[s] = specid[sb][s];
        sqv[s] = specq[sb][s];
      }
      float gA = g[lane][j], gB = g[lane + 64][j];
      float qvA = qv[lane],  qvB = qv[lane + 64];
      int   tA = tracked[lane], tB = tracked[lane + 64];
      float xrow = XXl[j * 65 + lane];
      float xnj  = XXl[j * 65 + j];
      // candidates: compacted untracked list entry (patched vs last-4 winners)
      u64 A0 = ~0ull, A1 = ~0ull;
      {
        int id = (int)(unsigned)(ck & 0xFFFFFFFFull);
        bool ok = (ck != ~0ull) && id != pw0 && id != pw1 && id != pw2 && id != pw3;
        if (ok) { A0 = ck; }
      }
      // tracked algebraic distances (expression preserved)
      if (lane < ns)      { float d = xnj - 2.f * gA + qvA; mrg2(A0, A1, pk(d, tA), ~0ull); }
      if (lane + 64 < ns) { float d = xnj - 2.f * gB + qvB; mrg2(A0, A1, pk(d, tB), ~0ull); }
      // DPP min-2 -> exact top-2 in lane 63
      dpp_round<0x111>(A0, A1);
      dpp_round<0x112>(A0, A1);
      dpp_round<0x114>(A0, A1);
      dpp_round<0x118>(A0, A1);
      dpp_round<0x142>(A0, A1);
      dpp_round<0x143>(A0, A1);
      const int r0 = (int)(unsigned)__builtin_amdgcn_readlane(
          (int)(unsigned)(A0 & 0xFFFFFFFFull), 63);
      const int r1 = (int)(unsigned)__builtin_amdgcn_readlane(
          (int)(unsigned)(A1 & 0xFFFFFFFFull), 63);
      if (lane == 63) {
        float2 o;
        o.x = sqrtf(fmaxf(__uint_as_float((unsigned)(A0 >> 32)), 0.f) + 1e-12f);
        o.y = sqrtf(fmaxf(__uint_as_float((unsigned)(A1 >> 32)), 0.f) + 1e-12f);
        *(float2*)(out + j * 2) = o;
      }
      // slot lookup + newness
      bool h0a = (lane < ns) && (tA == r0);
      bool h0b = (lane + 64 < ns) && (tB == r0);
      u64 mk0a = __ballot(h0a), mk0b = __ballot(h0b);
      bool new0 = (mk0a | mk0b) == 0ull;
      int sl0 = new0 ? ns
                     : (mk0a ? (__ffsll((unsigned long long)mk0a) - 1)
                             : (64 + __ffsll((unsigned long long)mk0b) - 1));
      bool h1a = (lane < ns) && (tA == r1);
      bool h1b = (lane + 64 < ns) && (tB == r1);
      u64 mk1a = __ballot(h1a), mk1b = __ballot(h1b);
      bool new1 = (mk1a | mk1b) == 0ull;
      int sl1 = new1 ? (ns + (new0 ? 1 : 0))
                     : (mk1a ? (__ffsll((unsigned long long)mk1a) - 1)
                             : (64 + __ffsll((unsigned long long)mk1b) - 1));
      // spec select over 6 (values bitwise identical to direct loads)
      bool hit0 = false, hit1 = false;
      float pv0 = 0.f, qq0 = 0.f, pv1 = 0.f, qq1 = 0.f;
#pragma unroll
      for (int s = 0; s < 6; s++) {
        bool h0 = (sid[s] == r0), h1 = (sid[s] == r1);
        pv0 = h0 ? sgv[s] : pv0;  qq0 = h0 ? sqv[s] : qq0;  hit0 |= h0;
        pv1 = h1 ? sgv[s] : pv1;  qq1 = h1 ? sqv[s] : qq1;  hit1 |= h1;
      }
      if (new0 && !hit0) { pv0 = PT[(size_t)r0 * NS + lane]; qq0 = Q[r0]; } // never taken
      if (new1 && !hit1) { pv1 = PT[(size_t)r1 * NS + lane]; qq1 = Q[r1]; }
      float gt0 = g[sl0][lane];
      float gt1 = g[sl1][lane];
      // phase 0: r0 / eps_b
      float gold0 = new0 ? (0.5f * (xdl + qq0 - pv0)) : gt0;
      float qold0 = new0 ? qq0
                         : __uint_as_float((unsigned)__builtin_amdgcn_readlane(
                               (int)__float_as_uint(sl0 < 64 ? qvA : qvB), sl0 & 63));
      float gj0 = __uint_as_float(
          (unsigned)__builtin_amdgcn_readlane((int)__float_as_uint(gold0), j));
      g[sl0][lane] = (1.f - eps_b) * gold0 + eps_b * xrow;
      if (lane == 0) {
        float om = 1.f - eps_b;
        qv[sl0] = om * om * qold0 + 2.f * eps_b * om * gj0 + eps_b * eps_b * xnj;
        tracked[sl0] = r0;
        if (new0) bitmap[r0 >> 5] |= 1u << (r0 & 31);
      }
      // phase 1: r1 / eps_n
      float gold1 = new1 ? (0.5f * (xdl + qq1 - pv1)) : gt1;
      float qold1 = new1 ? qq1
                         : __uint_as_float((unsigned)__builtin_amdgcn_readlane(
                               (int)__float_as_uint(sl1 < 64 ? qvA : qvB), sl1 & 63));
      float gj1 = __uint_as_float(
          (unsigned)__builtin_amdgcn_readlane((int)__float_as_uint(gold1), j));
      g[sl1][lane] = (1.f - eps_n) * gold1 + eps_n * xrow;
      if (lane == 0) {
        float on = 1.f - eps_n;
        qv[sl1] = on * on * qold1 + 2.f * eps_n * on * gj1 + eps_n * eps_n * xnj;
        tracked[sl1] = r1;
        if (new1) bitmap[r1 >> 5] |= 1u << (r1 & 31);
      }
      ns += (new0 ? 1 : 0) + (new1 ? 1 : 0);
      pw2 = pw0; pw3 = pw1; pw0 = r0; pw1 = r1;
      __hip_atomic_store(&done[j], 1, __ATOMIC_RELEASE,
                         __HIP_MEMORY_SCOPE_WORKGROUP);
    }
  } else {
    // ========== producers (wv=1: even t, wv=2: odd t), wait done[t-3] ==========
    for (int t = (wv == 1 ? 0 : 1); t < NS; t += 2) {
      if (t >= 3) {
        while (__hip_atomic_load(&done[t - 3], __ATOMIC_ACQUIRE,
                                 __HIP_MEMORY_SCOPE_WORKGROUP) == 0)
          __builtin_amdgcn_s_sleep(1);
      }
      const u64* Lr = L + (size_t)t * KL;
      u64 e0 = Lr[lane], e1 = Lr[lane + 64];
      u64 e2 = (lane < 8) ? Lr[128 + lane] : ~0ull;
      int i0 = (int)(unsigned)(e0 & 0xFFFFFFFFull);
      int i1 = (int)(unsigned)(e1 & 0xFFFFFFFFull);
      int i2 = (int)(unsigned)(e2 & 0xFFFFFFFFull);
      bool t0 = (e0 == ~0ull) || ((bitmap[i0 >> 5] >> (i0 & 31)) & 1u);
      bool t1 = (e1 == ~0ull) || ((bitmap[i1 >> 5] >> (i1 & 31)) & 1u);
      bool t2 = (e2 == ~0ull) || ((bitmap[i2 >> 5] >> (i2 & 31)) & 1u);
      u64 um0 = ~__ballot(t0), um1 = ~__ballot(t1), um2 = ~__ballot(t2);
      u64 below = (1ull << lane) - 1;
      int c0n = __popcll((unsigned long long)um0);
      int c1n = __popcll((unsigned long long)um1);
      int rank0 = __popcll((unsigned long long)(um0 & below));
      int rank1 = c0n + __popcll((unsigned long long)(um1 & below));
      int rank2 = c0n + c1n + __popcll((unsigned long long)(um2 & below));
      if (!t0 && rank0 < 16) cand16[t][rank0] = e0;
      if (!t1 && rank1 < 16) cand16[t][rank1] = e1;
      if (!t2 && rank2 < 16) cand16[t][rank2] = e2;
      int U = c0n + c1n + __popcll((unsigned long long)um2);
      if (lane < 16 && lane >= U) cand16[t][lane] = ~0ull;
      // spec: first-6-untracked PT/Q (U >= 136-126 = 10 >= 6 always)
      const int sb = t & 3;
      int ids[6];
#pragma unroll
      for (int s = 0; s < 6; s++)
        ids[s] = (int)(unsigned)(cand16[t][s] & 0xFFFFFFFFull);
#pragma unroll
      for (int s = 0; s < 6; s++)
        specg[sb][s][lane] = PT[(size_t)ids[s] * NS + lane];
      if (lane < 6) {
        specid[sb][lane] = ids[lane];
        specq[sb][lane] = Q[ids[lane]];
      }
      __hip_atomic_store(&ready[t], 1, __ATOMIC_RELEASE,
                         __HIP_MEMORY_SCOPE_WORKGROUP);
    }
  }
}

extern "C" void kernel_launch(void* const* d_in, const int* in_sizes, int n_in,
                              void* d_out, int out_size, void* d_ws, size_t ws_size,
                              hipStream_t stream) {
  const float* X  = (const float*)d_in[0];  // [64,256]
  const float* V  = (const float*)d_in[1];  // [100000,256]
  const int*  itp = (const int*)d_in[3];    // scalar it
  float* out = (float*)d_out;               // [64,2]

  char* ws = (char*)d_ws;
  size_t off = 0;
  auto alloc = [&](size_t bytes) -> void* {
    size_t o = (off + 255) & ~(size_t)255;
    off = o + bytes;
    return (void*)(ws + o);
  };
  float* P    = (float*)alloc((size_t)NS * N_NODES * sizeof(float)); // 25.6 MB
  float* PT   = (float*)alloc((size_t)NS * N_NODES * sizeof(float)); // 25.6 MB
  float* Q    = (float*)alloc((size_t)N_NODES * sizeof(float));
  float* XXp  = (float*)alloc((size_t)NS * NS * sizeof(float));
  u64*   SUMC = (u64*)alloc((size_t)NS * NCH * sizeof(u64));         // 800 KB
  u64*   Lst  = (u64*)alloc((size_t)NS * KL * sizeof(u64));          // 96 KB

  k_xx   <<<NS, NS, 0, stream>>>(X, XXp);
  k_dist <<<(N_NODES + 127) / 128, 256, 0, stream>>>(X, V, XXp, P, PT, Q, SUMC);
  k_build<<<NS, 1024, 0, stream>>>(SUMC, P, Lst);
  k_seq  <<<1, 192, 0, stream>>>(PT, Q, XXp, Lst, itp, out);
}